// Round 1
// baseline (3612.123 us; speedup 1.0000x reference)
//
#include <hip/hip_runtime.h>
#include <hip/hip_bf16.h>
#include <cstdint>

// Problem constants (fixed by setup_inputs)
#define N_NODES 102400
#define N_EDGES 1638400
#define N_REL   8
#define D0      256
#define D1      128
#define D2      64

// ---------------------------------------------------------------------------
// fill h[i] = bias[i & mask]  (bias folded into the scatter accumulator init)
__global__ __launch_bounds__(256) void fill_bias_k(float* __restrict__ h,
                                                   const float* __restrict__ bias,
                                                   int total, int mask) {
    int i = blockIdx.x * 256 + threadIdx.x;
    if (i < total) h[i] = bias[i & mask];
}

__global__ __launch_bounds__(256) void fill_scalar_k(float* __restrict__ h,
                                                     const float* __restrict__ bias,
                                                     int total) {
    int i = blockIdx.x * 256 + threadIdx.x;
    if (i < total) h[i] = bias[0];
}

// ---------------------------------------------------------------------------
// Tiled fp32 GEMM: C[N,DOUT] = A[N,DIN] @ B[DIN,DOUT], optional ReLU on A load.
// BM=128, BN=DOUT (128 or 64), BK=32, 256 threads, micro-tile TM=8 x TN=BN/16.
template<int DIN, int DOUT, bool RELU>
__global__ __launch_bounds__(256) void gemm_rel(const float* __restrict__ A,
                                                const float* __restrict__ B,
                                                float* __restrict__ C) {
    constexpr int BM = 128;
    constexpr int BK = 32;
    constexpr int BN = DOUT;
    constexpr int TM = 8;
    constexpr int TN = BN / 16;      // 8 (DOUT=128) or 4 (DOUT=64)

    __shared__ float As[BK][BM + 4]; // transposed A tile, padded
    __shared__ float Bs[BK][BN];

    const int tid  = threadIdx.x;
    const int row0 = blockIdx.x * BM;
    const int tm   = (tid / 16) * TM;
    const int tn   = (tid % 16) * TN;

    float acc[TM][TN];
#pragma unroll
    for (int i = 0; i < TM; ++i)
#pragma unroll
        for (int j = 0; j < TN; ++j) acc[i][j] = 0.f;

    for (int k0 = 0; k0 < DIN; k0 += BK) {
        // --- A tile: BM x BK floats, float4 loads, store transposed ---
        constexpr int A_F4 = (BM * BK) / 4;          // 1024
#pragma unroll
        for (int i = 0; i < A_F4 / 256; ++i) {
            int idx = tid + i * 256;
            int r   = idx / (BK / 4);
            int c4  = idx % (BK / 4);
            float4 v = *reinterpret_cast<const float4*>(
                &A[(size_t)(row0 + r) * DIN + k0 + c4 * 4]);
            if (RELU) {
                v.x = fmaxf(v.x, 0.f); v.y = fmaxf(v.y, 0.f);
                v.z = fmaxf(v.z, 0.f); v.w = fmaxf(v.w, 0.f);
            }
            As[c4 * 4 + 0][r] = v.x;
            As[c4 * 4 + 1][r] = v.y;
            As[c4 * 4 + 2][r] = v.z;
            As[c4 * 4 + 3][r] = v.w;
        }
        // --- B tile: BK x BN floats ---
        constexpr int B_F4 = (BK * BN) / 4;          // 1024 or 512
#pragma unroll
        for (int i = 0; i < B_F4 / 256; ++i) {
            int idx = tid + i * 256;
            int r   = idx / (BN / 4);
            int c4  = idx % (BN / 4);
            *reinterpret_cast<float4*>(&Bs[r][c4 * 4]) =
                *reinterpret_cast<const float4*>(&B[(size_t)(k0 + r) * DOUT + c4 * 4]);
        }
        __syncthreads();

#pragma unroll
        for (int k = 0; k < BK; ++k) {
            float a[TM], b[TN];
#pragma unroll
            for (int i = 0; i < TM; ++i) a[i] = As[k][tm + i];
#pragma unroll
            for (int j = 0; j < TN; ++j) b[j] = Bs[k][tn + j];
#pragma unroll
            for (int i = 0; i < TM; ++i)
#pragma unroll
                for (int j = 0; j < TN; ++j) acc[i][j] += a[i] * b[j];
        }
        __syncthreads();
    }

    // --- store C ---
#pragma unroll
    for (int i = 0; i < TM; ++i) {
        size_t base = (size_t)(row0 + tm + i) * DOUT + tn;
#pragma unroll
        for (int j = 0; j < TN; j += 4) {
            float4 v = make_float4(acc[i][j], acc[i][j + 1], acc[i][j + 2], acc[i][j + 3]);
            *reinterpret_cast<float4*>(&C[base + j]) = v;
        }
    }
}

// ---------------------------------------------------------------------------
// Edge scatter for one relation: h[dst,:] += ew * xw[src,:] for etype==rel
template<int DOUT>
__global__ __launch_bounds__(256) void edge_scatter(const int* __restrict__ src,
                                                    const int* __restrict__ dst,
                                                    const float* __restrict__ ew,
                                                    const int* __restrict__ et,
                                                    int rel,
                                                    const float* __restrict__ xw,
                                                    float* __restrict__ h) {
    constexpr int EPB = 256 / DOUT;             // edges per block
    const int lane = threadIdx.x % DOUT;
    const int sub  = threadIdx.x / DOUT;
    for (int e = blockIdx.x * EPB + sub; e < N_EDGES; e += gridDim.x * EPB) {
        if (et[e] != rel) continue;
        const int   s = src[e];
        const int   d = dst[e];
        const float w = ew[e];
        atomicAdd(&h[(size_t)d * DOUT + lane], w * xw[(size_t)s * DOUT + lane]);
    }
}

// ---------------------------------------------------------------------------
// xw3[n,r] = sum_d relu(h2[n,d]) * W3[r,d,0]      (tiny GEMM, all relations)
__global__ __launch_bounds__(256) void xw3_kernel(const float* __restrict__ h2,
                                                  const float* __restrict__ W3,
                                                  float* __restrict__ xw3) {
    __shared__ float w[N_REL][D2];
    for (int i = threadIdx.x; i < N_REL * D2; i += 256)
        w[i / D2][i % D2] = W3[i];
    __syncthreads();
    int g = blockIdx.x * 256 + threadIdx.x;     // g = n*8 + r
    if (g < N_NODES * N_REL) {
        int n = g >> 3, r = g & 7;
        const float* hp = &h2[(size_t)n * D2];
        float s = 0.f;
#pragma unroll
        for (int d = 0; d < D2; ++d) s += fmaxf(hp[d], 0.f) * w[r][d];
        xw3[g] = s;
    }
}

// Final layer scatter: out[dst] += ew * xw3[src, etype]  (single pass, all rel)
__global__ __launch_bounds__(256) void edge_scatter1(const int* __restrict__ src,
                                                     const int* __restrict__ dst,
                                                     const float* __restrict__ ew,
                                                     const int* __restrict__ et,
                                                     const float* __restrict__ xw3,
                                                     float* __restrict__ out) {
    int e = blockIdx.x * 256 + threadIdx.x;
    if (e < N_EDGES) {
        atomicAdd(&out[dst[e]], ew[e] * xw3[(size_t)src[e] * N_REL + et[e]]);
    }
}

// ---------------------------------------------------------------------------
extern "C" void kernel_launch(void* const* d_in, const int* in_sizes, int n_in,
                              void* d_out, int out_size, void* d_ws, size_t ws_size,
                              hipStream_t stream) {
    (void)in_sizes; (void)n_in; (void)out_size; (void)ws_size;

    const float* z    = (const float*)d_in[0];              // [N, 256]
    const int*   eidx = (const int*)d_in[1];                // [2, E]
    const float* ew   = (const float*)d_in[2];              // [E]
    const int*   et   = (const int*)d_in[3];                // [E]
    const float* W1   = (const float*)d_in[4];              // [8,256,128]
    const float* b1   = (const float*)d_in[5];              // [128]
    const float* W2   = (const float*)d_in[6];              // [8,128,64]
    const float* b2   = (const float*)d_in[7];              // [64]
    const float* W3   = (const float*)d_in[8];              // [8,64,1]
    const float* b3   = (const float*)d_in[9];              // [1]

    const int* src = eidx;
    const int* dst = eidx + N_EDGES;

    // Workspace layout (131 MB total):
    //   xw  : [N,128] fp32 = 52.4 MB  (per-relation transform, reused all layers)
    //   h1  : [N,128] fp32 = 52.4 MB
    //   h2  : [N, 64] fp32 = 26.2 MB
    char* ws = (char*)d_ws;
    float* xw = (float*)(ws);
    float* h1 = (float*)(ws + (size_t)N_NODES * D1 * 4);
    float* h2 = (float*)(ws + (size_t)N_NODES * D1 * 4 * 2);
    float* out = (float*)d_out;                             // [N] fp32

    // ---------------- Layer 1: 256 -> 128 ----------------
    {
        int total = N_NODES * D1;
        fill_bias_k<<<(total + 255) / 256, 256, 0, stream>>>(h1, b1, total, D1 - 1);
        for (int r = 0; r < N_REL; ++r) {
            gemm_rel<D0, D1, false><<<N_NODES / 128, 256, 0, stream>>>(
                z, W1 + (size_t)r * D0 * D1, xw);
            edge_scatter<D1><<<2048, 256, 0, stream>>>(src, dst, ew, et, r, xw, h1);
        }
    }
    // ---------------- Layer 2: 128 -> 64 (ReLU folded into A-load) ----------
    {
        int total = N_NODES * D2;
        fill_bias_k<<<(total + 255) / 256, 256, 0, stream>>>(h2, b2, total, D2 - 1);
        for (int r = 0; r < N_REL; ++r) {
            gemm_rel<D1, D2, true><<<N_NODES / 128, 256, 0, stream>>>(
                h1, W2 + (size_t)r * D1 * D2, xw);
            edge_scatter<D2><<<2048, 256, 0, stream>>>(src, dst, ew, et, r, xw, h2);
        }
    }
    // ---------------- Layer 3: 64 -> 1 (all relations at once) --------------
    {
        xw3_kernel<<<(N_NODES * N_REL + 255) / 256, 256, 0, stream>>>(h2, W3, xw);
        fill_scalar_k<<<(N_NODES + 255) / 256, 256, 0, stream>>>(out, b3, N_NODES);
        edge_scatter1<<<(N_EDGES + 255) / 256, 256, 0, stream>>>(src, dst, ew, et, xw, out);
    }
}

// Round 2
// 1974.724 us; speedup vs baseline: 1.8292x; 1.8292x over previous
//
#include <hip/hip_runtime.h>
#include <hip/hip_bf16.h>
#include <cstdint>

// Problem constants (fixed by setup_inputs)
#define N_NODES 102400
#define N_EDGES 1638400
#define N_REL   8
#define D0      256
#define D1      128
#define D2      64

#define NBUCKET   (N_REL * N_NODES)      // 819200 (rel, dst) buckets
#define SCAN_BLK  1024                   // elements per scan block
#define NSCAN_BLK (NBUCKET / SCAN_BLK)   // 800

// ---------------------------------------------------------------------------
__global__ __launch_bounds__(256) void fill0_k(int* __restrict__ p, int total) {
    int i = blockIdx.x * 256 + threadIdx.x;
    if (i < total) p[i] = 0;
}

// Histogram over (rel, dst) buckets
__global__ __launch_bounds__(256) void hist_k(const int* __restrict__ dst,
                                              const int* __restrict__ et,
                                              int* __restrict__ cnt) {
    int e = blockIdx.x * 256 + threadIdx.x;
    if (e < N_EDGES) atomicAdd(&cnt[et[e] * N_NODES + dst[e]], 1);
}

// Block-level exclusive scan: 1024 elements/block, 256 threads x 4 elems.
__global__ __launch_bounds__(256) void scan1_k(const int* __restrict__ cnt,
                                               int* __restrict__ off,
                                               int* __restrict__ part) {
    __shared__ int sA[256], sB[256];
    const int t    = threadIdx.x;
    const int base = blockIdx.x * SCAN_BLK + t * 4;
    int c0 = cnt[base + 0], c1 = cnt[base + 1], c2 = cnt[base + 2], c3 = cnt[base + 3];
    int sum = c0 + c1 + c2 + c3;
    sA[t] = sum;
    __syncthreads();
    int* s = sA; int* d = sB;
    for (int o = 1; o < 256; o <<= 1) {
        int v = s[t];
        if (t >= o) v += s[t - o];
        d[t] = v;
        __syncthreads();
        int* tmp = s; s = d; d = tmp;
    }
    int excl = s[t] - sum;                   // exclusive prefix of thread sums
    off[base + 0] = excl;
    off[base + 1] = excl + c0;
    off[base + 2] = excl + c0 + c1;
    off[base + 3] = excl + c0 + c1 + c2;
    if (t == 255) part[blockIdx.x] = s[255]; // block total
}

// Exclusive scan of the NSCAN_BLK block totals (single block).
__global__ __launch_bounds__(256) void scan2_k(int* __restrict__ part) {
    __shared__ int sA[256], sB[256];
    const int t = threadIdx.x;
    int c[4], sum = 0;
#pragma unroll
    for (int i = 0; i < 4; ++i) {
        int idx = t * 4 + i;
        c[i] = (idx < NSCAN_BLK) ? part[idx] : 0;
        sum += c[i];
    }
    sA[t] = sum;
    __syncthreads();
    int* s = sA; int* d = sB;
    for (int o = 1; o < 256; o <<= 1) {
        int v = s[t];
        if (t >= o) v += s[t - o];
        d[t] = v;
        __syncthreads();
        int* tmp = s; s = d; d = tmp;
    }
    int excl = s[t] - sum;
    int run = excl;
#pragma unroll
    for (int i = 0; i < 4; ++i) {
        int idx = t * 4 + i;
        if (idx < NSCAN_BLK) part[idx] = run;
        run += c[i];
    }
}

// Add block offsets; produce cursor copy; set sentinel.
__global__ __launch_bounds__(256) void scan3_k(int* __restrict__ off,
                                               const int* __restrict__ part,
                                               int* __restrict__ cursor) {
    int i = blockIdx.x * 256 + threadIdx.x;
    if (i < NBUCKET) {
        int v = off[i] + part[i / SCAN_BLK];
        off[i]    = v;
        cursor[i] = v;
    }
    if (i == 0) off[NBUCKET] = N_EDGES;
}

// Scatter edges into (rel,dst)-sorted order: es[pos] = {src, bits(ew)}
__global__ __launch_bounds__(256) void scatter_edges_k(const int* __restrict__ src,
                                                       const int* __restrict__ dst,
                                                       const float* __restrict__ ew,
                                                       const int* __restrict__ et,
                                                       int* __restrict__ cursor,
                                                       int2* __restrict__ es) {
    int e = blockIdx.x * 256 + threadIdx.x;
    if (e < N_EDGES) {
        int key = et[e] * N_NODES + dst[e];
        int pos = atomicAdd(&cursor[key], 1);
        es[pos] = make_int2(src[e], __float_as_int(ew[e]));
    }
}

// ---------------------------------------------------------------------------
// Tiled fp32 GEMM: C[N,DOUT] = A[N,DIN] @ B[DIN,DOUT], optional ReLU on A load.
template<int DIN, int DOUT, bool RELU>
__global__ __launch_bounds__(256) void gemm_rel(const float* __restrict__ A,
                                                const float* __restrict__ B,
                                                float* __restrict__ C) {
    constexpr int BM = 128;
    constexpr int BK = 32;
    constexpr int BN = DOUT;
    constexpr int TM = 8;
    constexpr int TN = BN / 16;

    __shared__ float As[BK][BM + 4];
    __shared__ float Bs[BK][BN];

    const int tid  = threadIdx.x;
    const int row0 = blockIdx.x * BM;
    const int tm   = (tid / 16) * TM;
    const int tn   = (tid % 16) * TN;

    float acc[TM][TN];
#pragma unroll
    for (int i = 0; i < TM; ++i)
#pragma unroll
        for (int j = 0; j < TN; ++j) acc[i][j] = 0.f;

    for (int k0 = 0; k0 < DIN; k0 += BK) {
        constexpr int A_F4 = (BM * BK) / 4;
#pragma unroll
        for (int i = 0; i < A_F4 / 256; ++i) {
            int idx = tid + i * 256;
            int r   = idx / (BK / 4);
            int c4  = idx % (BK / 4);
            float4 v = *reinterpret_cast<const float4*>(
                &A[(size_t)(row0 + r) * DIN + k0 + c4 * 4]);
            if (RELU) {
                v.x = fmaxf(v.x, 0.f); v.y = fmaxf(v.y, 0.f);
                v.z = fmaxf(v.z, 0.f); v.w = fmaxf(v.w, 0.f);
            }
            As[c4 * 4 + 0][r] = v.x;
            As[c4 * 4 + 1][r] = v.y;
            As[c4 * 4 + 2][r] = v.z;
            As[c4 * 4 + 3][r] = v.w;
        }
        constexpr int B_F4 = (BK * BN) / 4;
#pragma unroll
        for (int i = 0; i < B_F4 / 256; ++i) {
            int idx = tid + i * 256;
            int r   = idx / (BN / 4);
            int c4  = idx % (BN / 4);
            *reinterpret_cast<float4*>(&Bs[r][c4 * 4]) =
                *reinterpret_cast<const float4*>(&B[(size_t)(k0 + r) * DOUT + c4 * 4]);
        }
        __syncthreads();

#pragma unroll
        for (int k = 0; k < BK; ++k) {
            float a[TM], b[TN];
#pragma unroll
            for (int i = 0; i < TM; ++i) a[i] = As[k][tm + i];
#pragma unroll
            for (int j = 0; j < TN; ++j) b[j] = Bs[k][tn + j];
#pragma unroll
            for (int i = 0; i < TM; ++i)
#pragma unroll
                for (int j = 0; j < TN; ++j) acc[i][j] += a[i] * b[j];
        }
        __syncthreads();
    }

#pragma unroll
    for (int i = 0; i < TM; ++i) {
        size_t base = (size_t)(row0 + tm + i) * DOUT + tn;
#pragma unroll
        for (int j = 0; j < TN; j += 4) {
            float4 v = make_float4(acc[i][j], acc[i][j + 1], acc[i][j + 2], acc[i][j + 3]);
            *reinterpret_cast<float4*>(&C[base + j]) = v;
        }
    }
}

// ---------------------------------------------------------------------------
// CSR gather-reduce for one relation: one wave per dst node.
// FIRST: h[d] = bias + acc (write-only). else: h[d] += acc (skip empty segs).
template<int DOUT, bool FIRST>
__global__ __launch_bounds__(256) void agg_rel(const int* __restrict__ off,
                                               const int2* __restrict__ es,
                                               int rel,
                                               const float* __restrict__ xw,
                                               const float* __restrict__ bias,
                                               float* __restrict__ h) {
    const int wave = (blockIdx.x * 256 + threadIdx.x) >> 6;
    const int lane = threadIdx.x & 63;
    if (wave >= N_NODES) return;
    const int d   = wave;
    const int key = rel * N_NODES + d;
    const int beg = off[key], end = off[key + 1];
    if (!FIRST && beg == end) return;

    if (DOUT == 128) {
        float2 acc = make_float2(0.f, 0.f);
        for (int j = beg; j < end; ++j) {
            int2 e = es[j];
            float w = __int_as_float(e.y);
            float2 v = *reinterpret_cast<const float2*>(&xw[(size_t)e.x * 128 + lane * 2]);
            acc.x += w * v.x;
            acc.y += w * v.y;
        }
        float* hp = &h[(size_t)d * 128 + lane * 2];
        if (FIRST) {
            hp[0] = bias[lane * 2]     + acc.x;
            hp[1] = bias[lane * 2 + 1] + acc.y;
        } else {
            hp[0] += acc.x;
            hp[1] += acc.y;
        }
    } else {
        float acc = 0.f;
        for (int j = beg; j < end; ++j) {
            int2 e = es[j];
            acc += __int_as_float(e.y) * xw[(size_t)e.x * DOUT + lane];
        }
        float* hp = &h[(size_t)d * DOUT + lane];
        if (FIRST) *hp = bias[lane] + acc;
        else       *hp += acc;
    }
}

// ---------------------------------------------------------------------------
// xw3[n,r] = sum_d relu(h2[n,d]) * W3[r,d,0]
__global__ __launch_bounds__(256) void xw3_kernel(const float* __restrict__ h2,
                                                  const float* __restrict__ W3,
                                                  float* __restrict__ xw3) {
    __shared__ float w[N_REL][D2];
    for (int i = threadIdx.x; i < N_REL * D2; i += 256)
        w[i / D2][i % D2] = W3[i];
    __syncthreads();
    int g = blockIdx.x * 256 + threadIdx.x;
    if (g < N_NODES * N_REL) {
        int n = g >> 3, r = g & 7;
        const float* hp = &h2[(size_t)n * D2];
        float s = 0.f;
#pragma unroll
        for (int d = 0; d < D2; ++d) s += fmaxf(hp[d], 0.f) * w[r][d];
        xw3[g] = s;
    }
}

// Final layer: one thread per dst node walks its 8 relation segments.
__global__ __launch_bounds__(256) void final_k(const int* __restrict__ off,
                                               const int2* __restrict__ es,
                                               const float* __restrict__ xw3,
                                               const float* __restrict__ b3,
                                               float* __restrict__ out) {
    int d = blockIdx.x * 256 + threadIdx.x;
    if (d >= N_NODES) return;
    float acc = b3[0];
#pragma unroll
    for (int r = 0; r < N_REL; ++r) {
        int key = r * N_NODES + d;
        int end = off[key + 1];
        for (int j = off[key]; j < end; ++j) {
            int2 e = es[j];
            acc += __int_as_float(e.y) * xw3[(size_t)e.x * N_REL + r];
        }
    }
    out[d] = acc;
}

// ---------------------------------------------------------------------------
extern "C" void kernel_launch(void* const* d_in, const int* in_sizes, int n_in,
                              void* d_out, int out_size, void* d_ws, size_t ws_size,
                              hipStream_t stream) {
    (void)in_sizes; (void)n_in; (void)out_size; (void)ws_size;

    const float* z    = (const float*)d_in[0];
    const int*   eidx = (const int*)d_in[1];
    const float* ew   = (const float*)d_in[2];
    const int*   et   = (const int*)d_in[3];
    const float* W1   = (const float*)d_in[4];
    const float* b1   = (const float*)d_in[5];
    const float* W2   = (const float*)d_in[6];
    const float* b2   = (const float*)d_in[7];
    const float* W3   = (const float*)d_in[8];
    const float* b3   = (const float*)d_in[9];

    const int* src = eidx;
    const int* dst = eidx + N_EDGES;

    // Workspace layout (~151 MB):
    char* ws = (char*)d_ws;
    size_t o = 0;
    auto alloc = [&](size_t bytes) { char* p = ws + o; o += (bytes + 255) & ~(size_t)255; return p; };
    int*  off    = (int*) alloc((NBUCKET + 1) * sizeof(int));   // 3.3 MB
    int*  cnt    = (int*) alloc(NBUCKET * sizeof(int));         // 3.3 MB (also cursor)
    int*  part   = (int*) alloc(NSCAN_BLK * sizeof(int));       // 3.2 KB
    int2* es     = (int2*)alloc(N_EDGES * sizeof(int2));        // 13.1 MB
    float* xw    = (float*)alloc((size_t)N_NODES * D1 * 4);     // 52.4 MB
    float* h1    = (float*)alloc((size_t)N_NODES * D1 * 4);     // 52.4 MB
    float* h2    = (float*)alloc((size_t)N_NODES * D2 * 4);     // 26.2 MB
    float* out   = (float*)d_out;

    // ---- Build (rel,dst)-sorted CSR ----
    fill0_k<<<(NBUCKET + 255) / 256, 256, 0, stream>>>(cnt, NBUCKET);
    hist_k<<<(N_EDGES + 255) / 256, 256, 0, stream>>>(dst, et, cnt);
    scan1_k<<<NSCAN_BLK, 256, 0, stream>>>(cnt, off, part);
    scan2_k<<<1, 256, 0, stream>>>(part);
    scan3_k<<<(NBUCKET + 255) / 256, 256, 0, stream>>>(off, part, cnt /*cursor*/);
    scatter_edges_k<<<(N_EDGES + 255) / 256, 256, 0, stream>>>(src, dst, ew, et, cnt, es);

    constexpr int AGG_BLKS = N_NODES / 4;   // 4 waves per 256-thread block

    // ---- Layer 1: 256 -> 128 ----
    for (int r = 0; r < N_REL; ++r) {
        gemm_rel<D0, D1, false><<<N_NODES / 128, 256, 0, stream>>>(
            z, W1 + (size_t)r * D0 * D1, xw);
        if (r == 0)
            agg_rel<D1, true><<<AGG_BLKS, 256, 0, stream>>>(off, es, r, xw, b1, h1);
        else
            agg_rel<D1, false><<<AGG_BLKS, 256, 0, stream>>>(off, es, r, xw, b1, h1);
    }
    // ---- Layer 2: 128 -> 64 (ReLU folded into GEMM A-load) ----
    for (int r = 0; r < N_REL; ++r) {
        gemm_rel<D1, D2, true><<<N_NODES / 128, 256, 0, stream>>>(
            h1, W2 + (size_t)r * D1 * D2, xw);
        if (r == 0)
            agg_rel<D2, true><<<AGG_BLKS, 256, 0, stream>>>(off, es, r, xw, b2, h2);
        else
            agg_rel<D2, false><<<AGG_BLKS, 256, 0, stream>>>(off, es, r, xw, b2, h2);
    }
    // ---- Layer 3: 64 -> 1 ----
    xw3_kernel<<<(N_NODES * N_REL + 255) / 256, 256, 0, stream>>>(h2, W3, xw);
    final_k<<<(N_NODES + 255) / 256, 256, 0, stream>>>(off, es, xw, b3, out);
}

// Round 3
// 1331.940 us; speedup vs baseline: 2.7119x; 1.4826x over previous
//
#include <hip/hip_runtime.h>
#include <hip/hip_bf16.h>
#include <hip/hip_fp16.h>
#include <cstdint>

// Problem constants (fixed by setup_inputs)
#define N_NODES 102400
#define N_EDGES 1638400
#define N_REL   8
#define D0      256
#define D1      128
#define D2      64

#define NBUCKET   (N_REL * N_NODES)      // 819200 (rel, dst) buckets
#define SCAN_BLK  1024
#define NSCAN_BLK (NBUCKET / SCAN_BLK)   // 800

typedef __attribute__((ext_vector_type(8))) short          s16x8;
typedef __attribute__((ext_vector_type(8))) unsigned short u16x8;
typedef __attribute__((ext_vector_type(4))) float          f32x4;

__device__ __forceinline__ unsigned short f2bf(float f) {
    unsigned u = __float_as_uint(f);
    u += 0x7fffu + ((u >> 16) & 1u);           // RNE
    return (unsigned short)(u >> 16);
}
__device__ __forceinline__ float bf2f(unsigned s) {
    return __uint_as_float(s << 16);
}

// ---------------------------------------------------------------------------
__global__ __launch_bounds__(256) void fill0_k(int* __restrict__ p, int total) {
    int i = blockIdx.x * 256 + threadIdx.x;
    if (i < total) p[i] = 0;
}

__global__ __launch_bounds__(256) void hist_k(const int* __restrict__ dst,
                                              const int* __restrict__ et,
                                              int* __restrict__ cnt) {
    int e = blockIdx.x * 256 + threadIdx.x;
    if (e < N_EDGES) atomicAdd(&cnt[et[e] * N_NODES + dst[e]], 1);
}

__global__ __launch_bounds__(256) void scan1_k(const int* __restrict__ cnt,
                                               int* __restrict__ off,
                                               int* __restrict__ part) {
    __shared__ int sA[256], sB[256];
    const int t    = threadIdx.x;
    const int base = blockIdx.x * SCAN_BLK + t * 4;
    int c0 = cnt[base + 0], c1 = cnt[base + 1], c2 = cnt[base + 2], c3 = cnt[base + 3];
    int sum = c0 + c1 + c2 + c3;
    sA[t] = sum;
    __syncthreads();
    int* s = sA; int* d = sB;
    for (int o = 1; o < 256; o <<= 1) {
        int v = s[t];
        if (t >= o) v += s[t - o];
        d[t] = v;
        __syncthreads();
        int* tmp = s; s = d; d = tmp;
    }
    int excl = s[t] - sum;
    off[base + 0] = excl;
    off[base + 1] = excl + c0;
    off[base + 2] = excl + c0 + c1;
    off[base + 3] = excl + c0 + c1 + c2;
    if (t == 255) part[blockIdx.x] = s[255];
}

__global__ __launch_bounds__(256) void scan2_k(int* __restrict__ part) {
    __shared__ int sA[256], sB[256];
    const int t = threadIdx.x;
    int c[4], sum = 0;
#pragma unroll
    for (int i = 0; i < 4; ++i) {
        int idx = t * 4 + i;
        c[i] = (idx < NSCAN_BLK) ? part[idx] : 0;
        sum += c[i];
    }
    sA[t] = sum;
    __syncthreads();
    int* s = sA; int* d = sB;
    for (int o = 1; o < 256; o <<= 1) {
        int v = s[t];
        if (t >= o) v += s[t - o];
        d[t] = v;
        __syncthreads();
        int* tmp = s; s = d; d = tmp;
    }
    int excl = s[t] - sum;
    int run = excl;
#pragma unroll
    for (int i = 0; i < 4; ++i) {
        int idx = t * 4 + i;
        if (idx < NSCAN_BLK) part[idx] = run;
        run += c[i];
    }
}

__global__ __launch_bounds__(256) void scan3_k(int* __restrict__ off,
                                               const int* __restrict__ part,
                                               int* __restrict__ cursor) {
    int i = blockIdx.x * 256 + threadIdx.x;
    if (i < NBUCKET) {
        int v = off[i] + part[i / SCAN_BLK];
        off[i]    = v;
        cursor[i] = v;
    }
    if (i == 0) off[NBUCKET] = N_EDGES;
}

// Scatter edges into (rel,dst)-sorted order: split arrays {src:int, ew:half}
__global__ __launch_bounds__(256) void scatter2_k(const int* __restrict__ src,
                                                  const int* __restrict__ dst,
                                                  const float* __restrict__ ew,
                                                  const int* __restrict__ et,
                                                  int* __restrict__ cursor,
                                                  int* __restrict__ esrc,
                                                  __half* __restrict__ ewh) {
    int e = blockIdx.x * 256 + threadIdx.x;
    if (e < N_EDGES) {
        int key = et[e] * N_NODES + dst[e];
        int pos = atomicAdd(&cursor[key], 1);
        esrc[pos] = src[e];
        ewh[pos]  = __float2half(ew[e]);
    }
}

// ---------------------------------------------------------------------------
// fp32 -> bf16 convert, optional ReLU, vectorized float4 -> ushort4
template<bool RELU>
__global__ __launch_bounds__(256) void cvt_bf16_k(const float* __restrict__ in,
                                                  unsigned short* __restrict__ out,
                                                  int n4) {
    int i = blockIdx.x * 256 + threadIdx.x;
    if (i < n4) {
        float4 v = reinterpret_cast<const float4*>(in)[i];
        if (RELU) {
            v.x = fmaxf(v.x, 0.f); v.y = fmaxf(v.y, 0.f);
            v.z = fmaxf(v.z, 0.f); v.w = fmaxf(v.w, 0.f);
        }
        ushort4 o;
        o.x = f2bf(v.x); o.y = f2bf(v.y); o.z = f2bf(v.z); o.w = f2bf(v.w);
        reinterpret_cast<ushort4*>(out)[i] = o;
    }
}

// W[R][K][Nn] fp32 -> Wt[R][Nn][K] bf16 (transpose; tiny, launched once)
__global__ __launch_bounds__(256) void cvt_wT_k(const float* __restrict__ in,
                                                unsigned short* __restrict__ out,
                                                int K, int Nn, int total) {
    int o = blockIdx.x * 256 + threadIdx.x;
    if (o < total) {
        int kn = K * Nn;
        int r = o / kn, rem = o % kn;
        int n = rem / K, k = rem % K;
        out[o] = f2bf(in[r * kn + k * Nn + n]);
    }
}

// ---------------------------------------------------------------------------
// bf16 MFMA GEMM: C[N,DOUT](bf16) = A[N,DIN](bf16) @ Bt[DOUT,DIN]^T(bf16)
// BM=128, BN=DOUT, BK=64, 4 waves in 2x2, per-wave 4x(BN/32) fragments 16x16.
template<int DIN, int DOUT>
__global__ __launch_bounds__(256) void mfma_gemm(const unsigned short* __restrict__ A,
                                                 const unsigned short* __restrict__ Bt,
                                                 unsigned short* __restrict__ C) {
    constexpr int BM  = 128;
    constexpr int BK  = 64;
    constexpr int BN  = DOUT;
    constexpr int LDK = BK + 8;                 // pad: rows 4 banks apart
    constexpr int FM  = (BM / 2) / 16;          // 4
    constexpr int FN  = (BN / 2) / 16;          // 4 (BN=128) or 2 (BN=64)

    __shared__ __align__(16) unsigned short As[BM][LDK];
    __shared__ __align__(16) unsigned short Bs[BN][LDK];

    const int tid  = threadIdx.x;
    const int wave = tid >> 6;
    const int lane = tid & 63;
    const int lr   = lane & 15;
    const int kq   = lane >> 4;                 // 0..3
    const int wm   = (wave >> 1) * (BM / 2);
    const int wn   = (wave & 1) * (BN / 2);
    const int row0 = blockIdx.x * BM;

    f32x4 acc[FM][FN];
#pragma unroll
    for (int i = 0; i < FM; ++i)
#pragma unroll
        for (int j = 0; j < FN; ++j) acc[i][j] = (f32x4){0.f, 0.f, 0.f, 0.f};

    for (int kt = 0; kt < DIN; kt += BK) {
        // stage A tile: BM x BK bf16, u16x8 (16B) loads
        constexpr int NA = BM * BK / 8;         // 1024
#pragma unroll
        for (int i = 0; i < NA / 256; ++i) {
            int idx = tid + i * 256;
            int r = idx >> 3;                   // BK/8 = 8 chunks per row
            int c = (idx & 7) * 8;
            u16x8 v = *reinterpret_cast<const u16x8*>(&A[(size_t)(row0 + r) * DIN + kt + c]);
            *reinterpret_cast<u16x8*>(&As[r][c]) = v;
        }
        // stage B tile: BN x BK bf16 from Bt[DOUT][DIN]
        constexpr int NB = BN * BK / 8;         // 1024 or 512
#pragma unroll
        for (int i = 0; i < NB / 256; ++i) {
            int idx = tid + i * 256;
            int r = idx >> 3;
            int c = (idx & 7) * 8;
            u16x8 v = *reinterpret_cast<const u16x8*>(&Bt[(size_t)r * DIN + kt + c]);
            *reinterpret_cast<u16x8*>(&Bs[r][c]) = v;
        }
        __syncthreads();

#pragma unroll
        for (int ks = 0; ks < BK; ks += 32) {
            s16x8 af[FM], bfr[FN];
#pragma unroll
            for (int mi = 0; mi < FM; ++mi)
                af[mi] = *reinterpret_cast<const s16x8*>(&As[wm + mi * 16 + lr][ks + kq * 8]);
#pragma unroll
            for (int ni = 0; ni < FN; ++ni)
                bfr[ni] = *reinterpret_cast<const s16x8*>(&Bs[wn + ni * 16 + lr][ks + kq * 8]);
#pragma unroll
            for (int mi = 0; mi < FM; ++mi)
#pragma unroll
                for (int ni = 0; ni < FN; ++ni)
                    acc[mi][ni] = __builtin_amdgcn_mfma_f32_16x16x32_bf16(
                        af[mi], bfr[ni], acc[mi][ni], 0, 0, 0);
        }
        __syncthreads();
    }

    // store C (bf16). D layout: col = lane&15, row = (lane>>4)*4 + reg.
#pragma unroll
    for (int mi = 0; mi < FM; ++mi) {
#pragma unroll
        for (int ni = 0; ni < FN; ++ni) {
#pragma unroll
            for (int reg = 0; reg < 4; ++reg) {
                int rrow = row0 + wm + mi * 16 + kq * 4 + reg;
                int ccol = wn + ni * 16 + lr;
                C[(size_t)rrow * DOUT + ccol] = f2bf(acc[mi][ni][reg]);
            }
        }
    }
}

// ---------------------------------------------------------------------------
// CSR gather-reduce, one wave per dst node; xw in bf16, ew in fp16, h fp32.
template<int DOUT, bool FIRST>
__global__ __launch_bounds__(256) void agg2(const int* __restrict__ off,
                                            const int* __restrict__ esrc,
                                            const __half* __restrict__ ewh,
                                            int rel,
                                            const unsigned short* __restrict__ xw,
                                            const float* __restrict__ bias,
                                            float* __restrict__ h) {
    const int node = (blockIdx.x * 256 + threadIdx.x) >> 6;
    const int lane = threadIdx.x & 63;
    if (node >= N_NODES) return;
    const int key = rel * N_NODES + node;
    const int beg = off[key], end = off[key + 1];
    if (!FIRST && beg == end) return;

    if (DOUT == 128) {
        float ax = 0.f, ay = 0.f;
        for (int j = beg; j < end; ++j) {
            const int   s = esrc[j];
            const float w = __half2float(ewh[j]);
            const unsigned p = *reinterpret_cast<const unsigned*>(&xw[(size_t)s * 128 + lane * 2]);
            ax += w * bf2f(p & 0xffffu);
            ay += w * bf2f(p >> 16);
        }
        float* hp = &h[(size_t)node * 128 + lane * 2];
        if (FIRST) { hp[0] = bias[lane * 2] + ax; hp[1] = bias[lane * 2 + 1] + ay; }
        else       { hp[0] += ax;                 hp[1] += ay; }
    } else {
        float a = 0.f;
        for (int j = beg; j < end; ++j)
            a += __half2float(ewh[j]) * bf2f(xw[(size_t)esrc[j] * DOUT + lane]);
        float* hp = &h[(size_t)node * DOUT + lane];
        if (FIRST) *hp = bias[lane] + a;
        else       *hp += a;
    }
}

// ---------------------------------------------------------------------------
// xw3[n,r] = sum_d relu(h2[n,d]) * W3[r,d,0]   (fp32, tiny)
__global__ __launch_bounds__(256) void xw3_kernel(const float* __restrict__ h2,
                                                  const float* __restrict__ W3,
                                                  float* __restrict__ xw3) {
    __shared__ float w[N_REL][D2];
    for (int i = threadIdx.x; i < N_REL * D2; i += 256)
        w[i / D2][i % D2] = W3[i];
    __syncthreads();
    int g = blockIdx.x * 256 + threadIdx.x;
    if (g < N_NODES * N_REL) {
        int n = g >> 3, r = g & 7;
        const float* hp = &h2[(size_t)n * D2];
        float s = 0.f;
#pragma unroll
        for (int d = 0; d < D2; ++d) s += fmaxf(hp[d], 0.f) * w[r][d];
        xw3[g] = s;
    }
}

// Final layer: one thread per dst node walks its 8 relation segments.
__global__ __launch_bounds__(256) void final_k(const int* __restrict__ off,
                                               const int* __restrict__ esrc,
                                               const __half* __restrict__ ewh,
                                               const float* __restrict__ xw3,
                                               const float* __restrict__ b3,
                                               float* __restrict__ out) {
    int d = blockIdx.x * 256 + threadIdx.x;
    if (d >= N_NODES) return;
    float acc = b3[0];
#pragma unroll
    for (int r = 0; r < N_REL; ++r) {
        int key = r * N_NODES + d;
        int end = off[key + 1];
        for (int j = off[key]; j < end; ++j)
            acc += __half2float(ewh[j]) * xw3[(size_t)esrc[j] * N_REL + r];
    }
    out[d] = acc;
}

// ---------------------------------------------------------------------------
extern "C" void kernel_launch(void* const* d_in, const int* in_sizes, int n_in,
                              void* d_out, int out_size, void* d_ws, size_t ws_size,
                              hipStream_t stream) {
    (void)in_sizes; (void)n_in; (void)out_size; (void)ws_size;

    const float* z    = (const float*)d_in[0];
    const int*   eidx = (const int*)d_in[1];
    const float* ew   = (const float*)d_in[2];
    const int*   et   = (const int*)d_in[3];
    const float* W1   = (const float*)d_in[4];
    const float* b1   = (const float*)d_in[5];
    const float* W2   = (const float*)d_in[6];
    const float* b2   = (const float*)d_in[7];
    const float* W3   = (const float*)d_in[8];
    const float* b3   = (const float*)d_in[9];

    const int* src = eidx;
    const int* dst = eidx + N_EDGES;

    // Workspace layout (148.1 MB total):
    char* ws = (char*)d_ws;
    size_t o = 0;
    auto alloc = [&](size_t bytes) { char* p = ws + o; o += (bytes + 255) & ~(size_t)255; return p; };
    int*    off   = (int*)   alloc((NBUCKET + 1) * sizeof(int));       //  3.28 MB
    int*    cnt   = (int*)   alloc(NBUCKET * sizeof(int));             //  3.28 MB (cursor)
    int*    part  = (int*)   alloc(NSCAN_BLK * sizeof(int));           //  3.2 KB
    int*    esrc  = (int*)   alloc(N_EDGES * sizeof(int));             //  6.55 MB
    __half* ewh   = (__half*)alloc(N_EDGES * sizeof(__half));          //  3.28 MB
    unsigned short* Wt1 = (unsigned short*)alloc((size_t)N_REL * D0 * D1 * 2); // 0.52 MB
    unsigned short* Wt2 = (unsigned short*)alloc((size_t)N_REL * D1 * D2 * 2); // 0.13 MB
    unsigned short* xwb = (unsigned short*)alloc((size_t)N_NODES * D1 * 2);    // 26.2 MB
    float*  h1    = (float*) alloc((size_t)N_NODES * D1 * 4);          // 52.4 MB
    char*   R     =          alloc((size_t)N_NODES * D0 * 2);          // 52.4 MB (reused)
    // R usage: layer 1 = z_bf16 [N,256]; layers 2-3 = h1_bf16 [N,128] + h2 [N,64] f32
    unsigned short* z_bf  = (unsigned short*)R;
    unsigned short* h1_bf = (unsigned short*)R;
    float*          h2    = (float*)(R + (size_t)N_NODES * D1 * 2);
    float* out = (float*)d_out;

    // ---- Build (rel,dst)-sorted CSR ----
    fill0_k<<<(NBUCKET + 255) / 256, 256, 0, stream>>>(cnt, NBUCKET);
    hist_k<<<(N_EDGES + 255) / 256, 256, 0, stream>>>(dst, et, cnt);
    scan1_k<<<NSCAN_BLK, 256, 0, stream>>>(cnt, off, part);
    scan2_k<<<1, 256, 0, stream>>>(part);
    scan3_k<<<(NBUCKET + 255) / 256, 256, 0, stream>>>(off, part, cnt /*cursor*/);
    scatter2_k<<<(N_EDGES + 255) / 256, 256, 0, stream>>>(src, dst, ew, et, cnt, esrc, ewh);

    // ---- Weight + input conversions (bf16) ----
    cvt_wT_k<<<(N_REL * D0 * D1 + 255) / 256, 256, 0, stream>>>(W1, Wt1, D0, D1, N_REL * D0 * D1);
    cvt_wT_k<<<(N_REL * D1 * D2 + 255) / 256, 256, 0, stream>>>(W2, Wt2, D1, D2, N_REL * D1 * D2);
    {
        int n4 = N_NODES * D0 / 4;
        cvt_bf16_k<false><<<(n4 + 255) / 256, 256, 0, stream>>>(z, z_bf, n4);
    }

    constexpr int AGG_BLKS = N_NODES / 4;   // 4 waves per 256-thread block

    // ---- Layer 1: 256 -> 128 (bf16 MFMA) ----
    for (int r = 0; r < N_REL; ++r) {
        mfma_gemm<D0, D1><<<N_NODES / 128, 256, 0, stream>>>(
            z_bf, Wt1 + (size_t)r * D0 * D1, xwb);
        if (r == 0)
            agg2<D1, true><<<AGG_BLKS, 256, 0, stream>>>(off, esrc, ewh, r, xwb, b1, h1);
        else
            agg2<D1, false><<<AGG_BLKS, 256, 0, stream>>>(off, esrc, ewh, r, xwb, b1, h1);
    }
    // ---- ReLU(h1) -> bf16 (overwrites z_bf region, now dead) ----
    {
        int n4 = N_NODES * D1 / 4;
        cvt_bf16_k<true><<<(n4 + 255) / 256, 256, 0, stream>>>(h1, h1_bf, n4);
    }
    // ---- Layer 2: 128 -> 64 (bf16 MFMA) ----
    for (int r = 0; r < N_REL; ++r) {
        mfma_gemm<D1, D2><<<N_NODES / 128, 256, 0, stream>>>(
            h1_bf, Wt2 + (size_t)r * D1 * D2, xwb);
        if (r == 0)
            agg2<D2, true><<<AGG_BLKS, 256, 0, stream>>>(off, esrc, ewh, r, xwb, b2, h2);
        else
            agg2<D2, false><<<AGG_BLKS, 256, 0, stream>>>(off, esrc, ewh, r, xwb, b2, h2);
    }
    // ---- Layer 3: 64 -> 1 (fp32, tiny) ----
    float* xw3f = (float*)xwb;              // 3.3 MB, region free now
    xw3_kernel<<<(N_NODES * N_REL + 255) / 256, 256, 0, stream>>>(h2, W3, xw3f);
    final_k<<<(N_NODES + 255) / 256, 256, 0, stream>>>(off, esrc, ewh, xw3f, b3, out);
}

// Round 4
// 1025.916 us; speedup vs baseline: 3.5209x; 1.2983x over previous
//
#include <hip/hip_runtime.h>
#include <hip/hip_bf16.h>
#include <hip/hip_fp16.h>
#include <cstdint>

// Problem constants (fixed by setup_inputs)
#define N_NODES 102400
#define N_EDGES 1638400
#define N_REL   8
#define D0      256
#define D1      128
#define D2      64

#define NBUCKET   (N_REL * N_NODES)      // 819200 (dst, rel) buckets: key = dst*8 + rel
#define SCAN_BLK  1024
#define NSCAN_BLK (NBUCKET / SCAN_BLK)   // 800

typedef __attribute__((ext_vector_type(8))) short          s16x8;
typedef __attribute__((ext_vector_type(8))) unsigned short u16x8;
typedef __attribute__((ext_vector_type(4))) float          f32x4;

__device__ __forceinline__ unsigned short f2bf(float f) {
    unsigned u = __float_as_uint(f);
    u += 0x7fffu + ((u >> 16) & 1u);           // RNE
    return (unsigned short)(u >> 16);
}
__device__ __forceinline__ float bf2f(unsigned s) {
    return __uint_as_float(s << 16);
}
__device__ __forceinline__ float h2f_bits(unsigned short u) {
    __half_raw r; r.x = u;
    return __half2float(__half(r));
}

// ---------------------------------------------------------------------------
__global__ __launch_bounds__(256) void fill0_k(int* __restrict__ p, int total) {
    int i = blockIdx.x * 256 + threadIdx.x;
    if (i < total) p[i] = 0;
}

// Histogram over (dst, rel) buckets
__global__ __launch_bounds__(256) void hist_k(const int* __restrict__ dst,
                                              const int* __restrict__ et,
                                              int* __restrict__ cnt) {
    int e = blockIdx.x * 256 + threadIdx.x;
    if (e < N_EDGES) atomicAdd(&cnt[dst[e] * N_REL + et[e]], 1);
}

__global__ __launch_bounds__(256) void scan1_k(const int* __restrict__ cnt,
                                               int* __restrict__ off,
                                               int* __restrict__ part) {
    __shared__ int sA[256], sB[256];
    const int t    = threadIdx.x;
    const int base = blockIdx.x * SCAN_BLK + t * 4;
    int c0 = cnt[base + 0], c1 = cnt[base + 1], c2 = cnt[base + 2], c3 = cnt[base + 3];
    int sum = c0 + c1 + c2 + c3;
    sA[t] = sum;
    __syncthreads();
    int* s = sA; int* d = sB;
    for (int o = 1; o < 256; o <<= 1) {
        int v = s[t];
        if (t >= o) v += s[t - o];
        d[t] = v;
        __syncthreads();
        int* tmp = s; s = d; d = tmp;
    }
    int excl = s[t] - sum;
    off[base + 0] = excl;
    off[base + 1] = excl + c0;
    off[base + 2] = excl + c0 + c1;
    off[base + 3] = excl + c0 + c1 + c2;
    if (t == 255) part[blockIdx.x] = s[255];
}

__global__ __launch_bounds__(256) void scan2_k(int* __restrict__ part) {
    __shared__ int sA[256], sB[256];
    const int t = threadIdx.x;
    int c[4], sum = 0;
#pragma unroll
    for (int i = 0; i < 4; ++i) {
        int idx = t * 4 + i;
        c[i] = (idx < NSCAN_BLK) ? part[idx] : 0;
        sum += c[i];
    }
    sA[t] = sum;
    __syncthreads();
    int* s = sA; int* d = sB;
    for (int o = 1; o < 256; o <<= 1) {
        int v = s[t];
        if (t >= o) v += s[t - o];
        d[t] = v;
        __syncthreads();
        int* tmp = s; s = d; d = tmp;
    }
    int excl = s[t] - sum;
    int run = excl;
#pragma unroll
    for (int i = 0; i < 4; ++i) {
        int idx = t * 4 + i;
        if (idx < NSCAN_BLK) part[idx] = run;
        run += c[i];
    }
}

__global__ __launch_bounds__(256) void scan3_k(int* __restrict__ off,
                                               const int* __restrict__ part,
                                               int* __restrict__ cursor) {
    int i = blockIdx.x * 256 + threadIdx.x;
    if (i < NBUCKET) {
        int v = off[i] + part[i / SCAN_BLK];
        off[i]    = v;
        cursor[i] = v;
    }
    if (i == 0) off[NBUCKET] = N_EDGES;
}

// Scatter edges into (dst,rel)-sorted order, packed 4B:
//   pack = (half_bits(ew) << 17) | src   (ew >= 0 so half sign bit = 0; src < 2^17)
__global__ __launch_bounds__(256) void scatter_pack_k(const int* __restrict__ src,
                                                      const int* __restrict__ dst,
                                                      const float* __restrict__ ew,
                                                      const int* __restrict__ et,
                                                      int* __restrict__ cursor,
                                                      unsigned* __restrict__ ep) {
    int e = blockIdx.x * 256 + threadIdx.x;
    if (e < N_EDGES) {
        int key = dst[e] * N_REL + et[e];
        int pos = atomicAdd(&cursor[key], 1);
        __half h = __float2half(ew[e]);
        unsigned hb = (unsigned)(__half_raw(h).x);
        ep[pos] = (hb << 17) | (unsigned)src[e];
    }
}

// ---------------------------------------------------------------------------
// fp32 -> bf16 convert (vectorized float4 -> ushort4)
__global__ __launch_bounds__(256) void cvt_bf16_k(const float* __restrict__ in,
                                                  unsigned short* __restrict__ out,
                                                  int n4) {
    int i = blockIdx.x * 256 + threadIdx.x;
    if (i < n4) {
        float4 v = reinterpret_cast<const float4*>(in)[i];
        ushort4 o;
        o.x = f2bf(v.x); o.y = f2bf(v.y); o.z = f2bf(v.z); o.w = f2bf(v.w);
        reinterpret_cast<ushort4*>(out)[i] = o;
    }
}

// W[R][K][Nn] fp32 -> Wt[R][Nn][K] bf16 (transpose; tiny, launched once)
__global__ __launch_bounds__(256) void cvt_wT_k(const float* __restrict__ in,
                                                unsigned short* __restrict__ out,
                                                int K, int Nn, int total) {
    int o = blockIdx.x * 256 + threadIdx.x;
    if (o < total) {
        int kn = K * Nn;
        int r = o / kn, rem = o % kn;
        int n = rem / K, k = rem % K;
        out[o] = f2bf(in[r * kn + k * Nn + n]);
    }
}

// ---------------------------------------------------------------------------
// bf16 MFMA GEMM, batched over blockIdx.y = relation-in-group:
//   C[y][N,DOUT](bf16) = A[N,DIN](bf16) @ Bt[y][DOUT,DIN]^T(bf16)
template<int DIN, int DOUT>
__global__ __launch_bounds__(256) void mfma_gemm_b(const unsigned short* __restrict__ A,
                                                   const unsigned short* __restrict__ Bt0,
                                                   unsigned short* __restrict__ C0) {
    constexpr int BM  = 128;
    constexpr int BK  = 64;
    constexpr int BN  = DOUT;
    constexpr int LDK = BK + 8;
    constexpr int FM  = (BM / 2) / 16;          // 4
    constexpr int FN  = (BN / 2) / 16;          // 4 (BN=128) or 2 (BN=64)

    __shared__ __align__(16) unsigned short As[BM][LDK];
    __shared__ __align__(16) unsigned short Bs[BN][LDK];

    const unsigned short* Bt = Bt0 + (size_t)blockIdx.y * DIN * DOUT;
    unsigned short*       C  = C0  + (size_t)blockIdx.y * N_NODES * DOUT;

    const int tid  = threadIdx.x;
    const int wave = tid >> 6;
    const int lane = tid & 63;
    const int lr   = lane & 15;
    const int kq   = lane >> 4;
    const int wm   = (wave >> 1) * (BM / 2);
    const int wn   = (wave & 1) * (BN / 2);
    const int row0 = blockIdx.x * BM;

    f32x4 acc[FM][FN];
#pragma unroll
    for (int i = 0; i < FM; ++i)
#pragma unroll
        for (int j = 0; j < FN; ++j) acc[i][j] = (f32x4){0.f, 0.f, 0.f, 0.f};

    for (int kt = 0; kt < DIN; kt += BK) {
        constexpr int NA = BM * BK / 8;
#pragma unroll
        for (int i = 0; i < NA / 256; ++i) {
            int idx = tid + i * 256;
            int r = idx >> 3;
            int c = (idx & 7) * 8;
            u16x8 v = *reinterpret_cast<const u16x8*>(&A[(size_t)(row0 + r) * DIN + kt + c]);
            *reinterpret_cast<u16x8*>(&As[r][c]) = v;
        }
        constexpr int NB = BN * BK / 8;
#pragma unroll
        for (int i = 0; i < NB / 256; ++i) {
            int idx = tid + i * 256;
            int r = idx >> 3;
            int c = (idx & 7) * 8;
            u16x8 v = *reinterpret_cast<const u16x8*>(&Bt[(size_t)r * DIN + kt + c]);
            *reinterpret_cast<u16x8*>(&Bs[r][c]) = v;
        }
        __syncthreads();

#pragma unroll
        for (int ks = 0; ks < BK; ks += 32) {
            s16x8 af[FM], bfr[FN];
#pragma unroll
            for (int mi = 0; mi < FM; ++mi)
                af[mi] = *reinterpret_cast<const s16x8*>(&As[wm + mi * 16 + lr][ks + kq * 8]);
#pragma unroll
            for (int ni = 0; ni < FN; ++ni)
                bfr[ni] = *reinterpret_cast<const s16x8*>(&Bs[wn + ni * 16 + lr][ks + kq * 8]);
#pragma unroll
            for (int mi = 0; mi < FM; ++mi)
#pragma unroll
                for (int ni = 0; ni < FN; ++ni)
                    acc[mi][ni] = __builtin_amdgcn_mfma_f32_16x16x32_bf16(
                        af[mi], bfr[ni], acc[mi][ni], 0, 0, 0);
        }
        __syncthreads();
    }

#pragma unroll
    for (int mi = 0; mi < FM; ++mi) {
#pragma unroll
        for (int ni = 0; ni < FN; ++ni) {
#pragma unroll
            for (int reg = 0; reg < 4; ++reg) {
                int rrow = row0 + wm + mi * 16 + kq * 4 + reg;
                int ccol = wn + ni * 16 + lr;
                C[(size_t)rrow * DOUT + ccol] = f2bf(acc[mi][ni][reg]);
            }
        }
    }
}

// ---------------------------------------------------------------------------
// Grouped CSR gather-reduce: one wave per dst node, G relations [g0, g0+G).
// FIRST: acc starts at bias.  RELUOUT (layer-1 last group): h_out = bf16(relu(hf + acc)).
// Middle: hf += acc (skip if the whole group range is empty).
template<int DOUT, bool FIRST, bool RELUOUT>
__global__ __launch_bounds__(256) void agg_g(const int* __restrict__ off,
                                             const unsigned* __restrict__ ep,
                                             int g0, int G,
                                             const unsigned short* __restrict__ xw,
                                             const float* __restrict__ bias,
                                             float* __restrict__ hf,
                                             unsigned short* __restrict__ hb) {
    const int node = (blockIdx.x * 256 + threadIdx.x) >> 6;
    const int lane = threadIdx.x & 63;
    if (node >= N_NODES) return;
    const int base = node * N_REL + g0;
    const int gbeg = off[base];
    if (!FIRST && !RELUOUT) {
        if (gbeg == off[base + G]) return;      // nothing to add, hf already valid
    }
    constexpr size_t XSTR = (size_t)N_NODES * DOUT;

    if (DOUT == 128) {
        float ax, ay;
        if (FIRST) { ax = bias[lane * 2]; ay = bias[lane * 2 + 1]; }
        else       { ax = 0.f;            ay = 0.f; }
        int j = gbeg;
        for (int r = 0; r < G; ++r) {
            const int e1 = off[base + r + 1];
            const unsigned short* xr = xw + (size_t)r * XSTR;
            for (; j < e1; ++j) {
                unsigned p = ep[j];
                int   s = p & 0x1FFFF;
                float w = h2f_bits((unsigned short)(p >> 17));
                unsigned v = *reinterpret_cast<const unsigned*>(&xr[(size_t)s * 128 + lane * 2]);
                ax += w * bf2f(v & 0xffffu);
                ay += w * bf2f(v >> 16);
            }
        }
        if (!FIRST) {
            float2 h0 = *reinterpret_cast<const float2*>(&hf[(size_t)node * 128 + lane * 2]);
            ax += h0.x; ay += h0.y;
        }
        if (RELUOUT) {
            unsigned pk = (unsigned)f2bf(fmaxf(ax, 0.f)) |
                          ((unsigned)f2bf(fmaxf(ay, 0.f)) << 16);
            *reinterpret_cast<unsigned*>(&hb[(size_t)node * 128 + lane * 2]) = pk;
        } else {
            *reinterpret_cast<float2*>(&hf[(size_t)node * 128 + lane * 2]) =
                make_float2(ax, ay);
        }
    } else {  // DOUT == 64 (layer 2: never RELUOUT)
        float a = FIRST ? bias[lane] : 0.f;
        int j = gbeg;
        for (int r = 0; r < G; ++r) {
            const int e1 = off[base + r + 1];
            const unsigned short* xr = xw + (size_t)r * XSTR;
            for (; j < e1; ++j) {
                unsigned p = ep[j];
                int   s = p & 0x1FFFF;
                float w = h2f_bits((unsigned short)(p >> 17));
                a += w * bf2f(xr[(size_t)s * 64 + lane]);
            }
        }
        if (!FIRST) a += hf[(size_t)node * 64 + lane];
        hf[(size_t)node * 64 + lane] = a;
    }
}

// ---------------------------------------------------------------------------
// xw3[n,r] = sum_d relu(h2[n,d]) * W3[r,d,0]   (fp32, tiny)
__global__ __launch_bounds__(256) void xw3_kernel(const float* __restrict__ h2,
                                                  const float* __restrict__ W3,
                                                  float* __restrict__ xw3) {
    __shared__ float w[N_REL][D2];
    for (int i = threadIdx.x; i < N_REL * D2; i += 256)
        w[i / D2][i % D2] = W3[i];
    __syncthreads();
    int g = blockIdx.x * 256 + threadIdx.x;
    if (g < N_NODES * N_REL) {
        int n = g >> 3, r = g & 7;
        const float* hp = &h2[(size_t)n * D2];
        float s = 0.f;
#pragma unroll
        for (int d = 0; d < D2; ++d) s += fmaxf(hp[d], 0.f) * w[r][d];
        xw3[g] = s;
    }
}

// Final layer: one thread per dst node; its 8 relation segments are contiguous.
__global__ __launch_bounds__(256) void final_k(const int* __restrict__ off,
                                               const unsigned* __restrict__ ep,
                                               const float* __restrict__ xw3,
                                               const float* __restrict__ b3,
                                               float* __restrict__ out) {
    int d = blockIdx.x * 256 + threadIdx.x;
    if (d >= N_NODES) return;
    float acc = b3[0];
    const int base = d * N_REL;
    int j = off[base];
#pragma unroll
    for (int r = 0; r < N_REL; ++r) {
        const int e1 = off[base + r + 1];
        for (; j < e1; ++j) {
            unsigned p = ep[j];
            int   s = p & 0x1FFFF;
            float w = h2f_bits((unsigned short)(p >> 17));
            acc += w * xw3[(size_t)s * N_REL + r];
        }
    }
    out[d] = acc;
}

// ---------------------------------------------------------------------------
extern "C" void kernel_launch(void* const* d_in, const int* in_sizes, int n_in,
                              void* d_out, int out_size, void* d_ws, size_t ws_size,
                              hipStream_t stream) {
    (void)in_sizes; (void)n_in; (void)out_size;

    const float* z    = (const float*)d_in[0];
    const int*   eidx = (const int*)d_in[1];
    const float* ew   = (const float*)d_in[2];
    const int*   et   = (const int*)d_in[3];
    const float* W1   = (const float*)d_in[4];
    const float* b1   = (const float*)d_in[5];
    const float* W2   = (const float*)d_in[6];
    const float* b2   = (const float*)d_in[7];
    const float* W3   = (const float*)d_in[8];
    const float* b3   = (const float*)d_in[9];

    const int* src = eidx;
    const int* dst = eidx + N_EDGES;

    // ---- choose relation-group size G by available workspace ----
    auto pad = [](size_t b) { return (b + 255) & ~(size_t)255; };
    const size_t fixed =
        pad((size_t)(NBUCKET + 1) * 4) + pad((size_t)NBUCKET * 4) + pad((size_t)NSCAN_BLK * 4) +
        pad((size_t)N_EDGES * 4) + pad((size_t)N_REL * D0 * D1 * 2) + pad((size_t)N_REL * D1 * D2 * 2) +
        pad((size_t)N_NODES * D1 * 4) + pad((size_t)N_NODES * D0 * 2);
    const size_t per_rel = (size_t)N_NODES * D1 * 2;   // 26.2 MB xw buffer per relation
    int G = 1;
    if (ws_size >= fixed + pad(4 * per_rel) + (1u << 20)) G = 4;
    else if (ws_size >= fixed + pad(2 * per_rel) + (1u << 20)) G = 2;
    const int NG = N_REL / G;

    // ---- workspace layout ----
    char* ws = (char*)d_ws;
    size_t o = 0;
    auto alloc = [&](size_t bytes) { char* p = ws + o; o += (bytes + 255) & ~(size_t)255; return p; };
    int*      off    = (int*)      alloc((size_t)(NBUCKET + 1) * 4);
    int*      cnt    = (int*)      alloc((size_t)NBUCKET * 4);          // also cursor
    int*      part   = (int*)      alloc((size_t)NSCAN_BLK * 4);
    unsigned* ep     = (unsigned*) alloc((size_t)N_EDGES * 4);
    unsigned short* Wt1 = (unsigned short*)alloc((size_t)N_REL * D0 * D1 * 2);
    unsigned short* Wt2 = (unsigned short*)alloc((size_t)N_REL * D1 * D2 * 2);
    unsigned short* xw_all = (unsigned short*)alloc((size_t)G * per_rel);   // G x [N,D1] bf16
    char*     Rh     =           alloc((size_t)N_NODES * D1 * 4);       // h1 f32 -> h2 f32
    char*     Rz     =           alloc((size_t)N_NODES * D0 * 2);       // z bf16 -> h1 bf16
    float*          h1f  = (float*)Rh;
    float*          h2f  = (float*)Rh;                                  // h1f dead when h2f live
    unsigned short* z_bf = (unsigned short*)Rz;
    unsigned short* h1b  = (unsigned short*)Rz;                         // z_bf dead when h1b live
    unsigned short* xw2  = xw_all;                                      // layer-2 xw (G x [N,D2])
    float*          xw3f = (float*)xw_all;                              // layer-3 (region free)
    float* out = (float*)d_out;

    // ---- Build (dst,rel)-sorted CSR ----
    fill0_k<<<(NBUCKET + 255) / 256, 256, 0, stream>>>(cnt, NBUCKET);
    hist_k<<<(N_EDGES + 255) / 256, 256, 0, stream>>>(dst, et, cnt);
    scan1_k<<<NSCAN_BLK, 256, 0, stream>>>(cnt, off, part);
    scan2_k<<<1, 256, 0, stream>>>(part);
    scan3_k<<<(NBUCKET + 255) / 256, 256, 0, stream>>>(off, part, cnt /*cursor*/);
    scatter_pack_k<<<(N_EDGES + 255) / 256, 256, 0, stream>>>(src, dst, ew, et, cnt, ep);

    // ---- conversions ----
    cvt_wT_k<<<(N_REL * D0 * D1 + 255) / 256, 256, 0, stream>>>(W1, Wt1, D0, D1, N_REL * D0 * D1);
    cvt_wT_k<<<(N_REL * D1 * D2 + 255) / 256, 256, 0, stream>>>(W2, Wt2, D1, D2, N_REL * D1 * D2);
    cvt_bf16_k<<<(N_NODES * D0 / 4 + 255) / 256, 256, 0, stream>>>(z, z_bf, N_NODES * D0 / 4);

    constexpr int AGG_BLKS = N_NODES / 4;       // 4 waves (nodes) per 256-thread block

    // ---- Layer 1: 256 -> 128 ----
    for (int g = 0; g < NG; ++g) {
        const int g0 = g * G;
        mfma_gemm_b<D0, D1><<<dim3(N_NODES / 128, G), 256, 0, stream>>>(
            z_bf, Wt1 + (size_t)g0 * D0 * D1, xw_all);
        const bool first = (g == 0), last = (g == NG - 1);
        if (first && !last)
            agg_g<D1, true,  false><<<AGG_BLKS, 256, 0, stream>>>(off, ep, g0, G, xw_all, b1, h1f, h1b);
        else if (!first && !last)
            agg_g<D1, false, false><<<AGG_BLKS, 256, 0, stream>>>(off, ep, g0, G, xw_all, b1, h1f, h1b);
        else  // last (NG>=2 always)
            agg_g<D1, false, true ><<<AGG_BLKS, 256, 0, stream>>>(off, ep, g0, G, xw_all, b1, h1f, h1b);
    }
    // ---- Layer 2: 128 -> 64 ----
    for (int g = 0; g < NG; ++g) {
        const int g0 = g * G;
        mfma_gemm_b<D1, D2><<<dim3(N_NODES / 128, G), 256, 0, stream>>>(
            h1b, Wt2 + (size_t)g0 * D1 * D2, xw2);
        if (g == 0)
            agg_g<D2, true,  false><<<AGG_BLKS, 256, 0, stream>>>(off, ep, g0, G, xw2, b2, h2f, nullptr);
        else
            agg_g<D2, false, false><<<AGG_BLKS, 256, 0, stream>>>(off, ep, g0, G, xw2, b2, h2f, nullptr);
    }
    // ---- Layer 3: 64 -> 1 ----
    xw3_kernel<<<(N_NODES * N_REL + 255) / 256, 256, 0, stream>>>(h2f, W3, xw3f);
    final_k<<<(N_NODES + 255) / 256, 256, 0, stream>>>(off, ep, xw3f, b3, out);
}

// Round 5
// 895.696 us; speedup vs baseline: 4.0328x; 1.1454x over previous
//
#include <hip/hip_runtime.h>
#include <hip/hip_bf16.h>
#include <hip/hip_fp16.h>
#include <cstdint>

// Problem constants (fixed by setup_inputs)
#define N_NODES 102400
#define N_EDGES 1638400
#define N_REL   8
#define D0      256
#define D1      128
#define D2      64

#define NBUCKET (N_REL * N_NODES)   // 819200 fine (dst,rel) keys: key = dst*8 + rel
#define WIN     256                 // dsts per coarse bin
#define NBIN    (N_NODES / WIN)     // 400
#define KPB     (WIN * N_REL)       // 2048 keys per bin
#define CHA     8192                // edges per partition block
#define NBLKA   (N_EDGES / CHA)     // 200 (exact)

typedef __attribute__((ext_vector_type(8))) short          s16x8;
typedef __attribute__((ext_vector_type(8))) unsigned short u16x8;
typedef __attribute__((ext_vector_type(4))) float          f32x4;

__device__ __forceinline__ unsigned short f2bf(float f) {
    unsigned u = __float_as_uint(f);
    u += 0x7fffu + ((u >> 16) & 1u);           // RNE
    return (unsigned short)(u >> 16);
}
__device__ __forceinline__ float h2f_bits(unsigned short u) {
    __half_raw r; r.x = u;
    return __half2float(__half(r));
}

// ---------------------------------------------------------------------------
__global__ __launch_bounds__(256) void fill0_k(int* __restrict__ p, int total) {
    int i = blockIdx.x * 256 + threadIdx.x;
    if (i < total) p[i] = 0;
}

// Coarse bin counts (bin = dst >> 8), LDS-aggregated
__global__ __launch_bounds__(256) void countA_k(const int* __restrict__ dst,
                                                int* __restrict__ bincnt) {
    __shared__ int h[NBIN];
    const int t  = threadIdx.x;
    const int e0 = blockIdx.x * CHA;
    for (int i = t; i < NBIN; i += 256) h[i] = 0;
    __syncthreads();
#pragma unroll
    for (int i = 0; i < CHA / 256; ++i) {
        int e = e0 + t + i * 256;
        if (e < N_EDGES) atomicAdd(&h[dst[e] >> 8], 1);
    }
    __syncthreads();
    for (int i = t; i < NBIN; i += 256) {
        int c = h[i];
        if (c) atomicAdd(&bincnt[i], c);
    }
}

__device__ __forceinline__ int block_scan_excl_512(int v, int* sA, int* sB, int t) {
    sA[t] = v;
    __syncthreads();
    int* s = sA; int* d = sB;
    for (int o = 1; o < 512; o <<= 1) {
        int x = s[t];
        if (t >= o) x += s[t - o];
        d[t] = x;
        __syncthreads();
        int* tmp = s; s = d; d = tmp;
    }
    return s[t] - v;
}

// Exclusive scan of 400 bin counts (single block)
__global__ __launch_bounds__(512) void scanB_k(const int* __restrict__ bincnt,
                                               int* __restrict__ binbase,
                                               int* __restrict__ bincur) {
    __shared__ int sA[512], sB[512];
    const int t = threadIdx.x;
    int v = (t < NBIN) ? bincnt[t] : 0;
    int excl = block_scan_excl_512(v, sA, sB, t);
    if (t < NBIN) { binbase[t] = excl; bincur[t] = excl; }
    if (t == 0) binbase[NBIN] = N_EDGES;
}

// Partition edges into coarse bins: temp[pos] = { (half(ew)<<17)|src , dst*8+rel }
__global__ __launch_bounds__(256) void scatterA_k(const int* __restrict__ src,
                                                  const int* __restrict__ dst,
                                                  const float* __restrict__ ew,
                                                  const int* __restrict__ et,
                                                  int* __restrict__ bincur,
                                                  uint2* __restrict__ temp) {
    __shared__ int h[NBIN];
    const int t  = threadIdx.x;
    const int e0 = blockIdx.x * CHA;
    for (int i = t; i < NBIN; i += 256) h[i] = 0;
    __syncthreads();
#pragma unroll
    for (int i = 0; i < CHA / 256; ++i) {
        int e = e0 + t + i * 256;
        if (e < N_EDGES) atomicAdd(&h[dst[e] >> 8], 1);
    }
    __syncthreads();
    for (int i = t; i < NBIN; i += 256) {
        int c = h[i];
        h[i] = c ? atomicAdd(&bincur[i], c) : 0;
    }
    __syncthreads();
#pragma unroll
    for (int i = 0; i < CHA / 256; ++i) {
        int e = e0 + t + i * 256;
        if (e < N_EDGES) {
            int d   = dst[e];
            int bin = d >> 8;
            unsigned hb = (unsigned)(__half_raw(__float2half(ew[e])).x);
            int pos = atomicAdd(&h[bin], 1);
            temp[pos] = make_uint2((hb << 17) | (unsigned)src[e],
                                   (unsigned)(d * N_REL + et[e]));
        }
    }
}

// Per-bin finalize: fine CSR offsets (coalesced write) + in-bin sorted scatter
__global__ __launch_bounds__(512) void passB_k(const uint2* __restrict__ temp,
                                               const int* __restrict__ binbase,
                                               int* __restrict__ off,
                                               unsigned* __restrict__ ep) {
    __shared__ int hist[KPB];
    __shared__ int sA[512], sB[512];
    const int b    = blockIdx.x;
    const int t    = threadIdx.x;
    const int beg  = binbase[b], end = binbase[b + 1];
    const int key0 = b * KPB;
#pragma unroll
    for (int i = 0; i < KPB / 512; ++i) hist[t + i * 512] = 0;
    __syncthreads();
    for (int j = beg + t; j < end; j += 512)
        atomicAdd(&hist[temp[j].y - key0], 1);
    __syncthreads();
    int c0 = hist[t * 4], c1 = hist[t * 4 + 1], c2 = hist[t * 4 + 2], c3 = hist[t * 4 + 3];
    int sum  = c0 + c1 + c2 + c3;
    int excl = block_scan_excl_512(sum, sA, sB, t) + beg;
    // all hist reads happened before the scan's barriers; safe to overwrite
    hist[t * 4]     = excl;
    hist[t * 4 + 1] = excl + c0;
    hist[t * 4 + 2] = excl + c0 + c1;
    hist[t * 4 + 3] = excl + c0 + c1 + c2;
    off[key0 + t * 4]     = excl;
    off[key0 + t * 4 + 1] = excl + c0;
    off[key0 + t * 4 + 2] = excl + c0 + c1;
    off[key0 + t * 4 + 3] = excl + c0 + c1 + c2;
    __syncthreads();
    for (int j = beg + t; j < end; j += 512) {
        uint2 e = temp[j];
        int pos = atomicAdd(&hist[e.y - key0], 1);
        ep[pos] = e.x;
    }
    if (b == 0 && t == 0) off[NBUCKET] = N_EDGES;
}

// ---------------------------------------------------------------------------
// W[R][K][Nn] fp32 -> Wt[R][Nn][K] bf16 (transpose; tiny, launched once)
__global__ __launch_bounds__(256) void cvt_wT_k(const float* __restrict__ in,
                                                unsigned short* __restrict__ out,
                                                int K, int Nn, int total) {
    int o = blockIdx.x * 256 + threadIdx.x;
    if (o < total) {
        int kn = K * Nn;
        int r = o / kn, rem = o % kn;
        int n = rem / K, k = rem % K;
        out[o] = f2bf(in[r * kn + k * Nn + n]);
    }
}

// ---------------------------------------------------------------------------
// bf16 MFMA GEMM, batched over blockIdx.y = relation-in-group.
// A is fp32 (converted during LDS staging) when AF32, else bf16.
// C written as fp16.
template<int DIN, int DOUT, bool AF32>
__global__ __launch_bounds__(256) void mfma_gemm_b(const void* __restrict__ Av,
                                                   const unsigned short* __restrict__ Bt0,
                                                   __half* __restrict__ C0) {
    constexpr int BM  = 128;
    constexpr int BK  = 64;
    constexpr int BN  = DOUT;
    constexpr int LDK = BK + 8;
    constexpr int FM  = (BM / 2) / 16;          // 4
    constexpr int FN  = (BN / 2) / 16;          // 4 (BN=128) or 2 (BN=64)

    __shared__ __align__(16) unsigned short As[BM][LDK];
    __shared__ __align__(16) unsigned short Bs[BN][LDK];

    const unsigned short* Bt = Bt0 + (size_t)blockIdx.y * DIN * DOUT;
    __half*               C  = C0  + (size_t)blockIdx.y * N_NODES * DOUT;

    const int tid  = threadIdx.x;
    const int wave = tid >> 6;
    const int lane = tid & 63;
    const int lr   = lane & 15;
    const int kq   = lane >> 4;
    const int wm   = (wave >> 1) * (BM / 2);
    const int wn   = (wave & 1) * (BN / 2);
    const int row0 = blockIdx.x * BM;

    f32x4 acc[FM][FN];
#pragma unroll
    for (int i = 0; i < FM; ++i)
#pragma unroll
        for (int j = 0; j < FN; ++j) acc[i][j] = (f32x4){0.f, 0.f, 0.f, 0.f};

    for (int kt = 0; kt < DIN; kt += BK) {
        constexpr int NA = BM * BK / 8;
#pragma unroll
        for (int i = 0; i < NA / 256; ++i) {
            int idx = tid + i * 256;
            int r = idx >> 3;
            int c = (idx & 7) * 8;
            u16x8 v;
            if constexpr (AF32) {
                const float* ap = (const float*)Av + (size_t)(row0 + r) * DIN + kt + c;
                float4 u0 = *reinterpret_cast<const float4*>(ap);
                float4 u1 = *reinterpret_cast<const float4*>(ap + 4);
                v[0] = (short)f2bf(u0.x); v[1] = (short)f2bf(u0.y);
                v[2] = (short)f2bf(u0.z); v[3] = (short)f2bf(u0.w);
                v[4] = (short)f2bf(u1.x); v[5] = (short)f2bf(u1.y);
                v[6] = (short)f2bf(u1.z); v[7] = (short)f2bf(u1.w);
            } else {
                v = *reinterpret_cast<const u16x8*>(
                    (const unsigned short*)Av + (size_t)(row0 + r) * DIN + kt + c);
            }
            *reinterpret_cast<u16x8*>(&As[r][c]) = v;
        }
        constexpr int NB = BN * BK / 8;
#pragma unroll
        for (int i = 0; i < NB / 256; ++i) {
            int idx = tid + i * 256;
            int r = idx >> 3;
            int c = (idx & 7) * 8;
            u16x8 v = *reinterpret_cast<const u16x8*>(&Bt[(size_t)r * DIN + kt + c]);
            *reinterpret_cast<u16x8*>(&Bs[r][c]) = v;
        }
        __syncthreads();

#pragma unroll
        for (int ks = 0; ks < BK; ks += 32) {
            s16x8 af[FM], bfr[FN];
#pragma unroll
            for (int mi = 0; mi < FM; ++mi)
                af[mi] = *reinterpret_cast<const s16x8*>(&As[wm + mi * 16 + lr][ks + kq * 8]);
#pragma unroll
            for (int ni = 0; ni < FN; ++ni)
                bfr[ni] = *reinterpret_cast<const s16x8*>(&Bs[wn + ni * 16 + lr][ks + kq * 8]);
#pragma unroll
            for (int mi = 0; mi < FM; ++mi)
#pragma unroll
                for (int ni = 0; ni < FN; ++ni)
                    acc[mi][ni] = __builtin_amdgcn_mfma_f32_16x16x32_bf16(
                        af[mi], bfr[ni], acc[mi][ni], 0, 0, 0);
        }
        __syncthreads();
    }

#pragma unroll
    for (int mi = 0; mi < FM; ++mi) {
#pragma unroll
        for (int ni = 0; ni < FN; ++ni) {
#pragma unroll
            for (int reg = 0; reg < 4; ++reg) {
                int rrow = row0 + wm + mi * 16 + kq * 4 + reg;
                int ccol = wn + ni * 16 + lr;
                C[(size_t)rrow * DOUT + ccol] = __float2half(acc[mi][ni][reg]);
            }
        }
    }
}

// ---------------------------------------------------------------------------
// Grouped CSR gather-reduce: one wave per dst node, G relations [g0, g0+G).
// FIRST: acc starts at bias. RELUOUT: h_out = bf16(relu(hprev + acc)).
template<int DOUT, bool FIRST, bool RELUOUT>
__global__ __launch_bounds__(256) void agg_g(const int* __restrict__ off,
                                             const unsigned* __restrict__ ep,
                                             int g0, int G,
                                             const __half* __restrict__ xw,
                                             const float* __restrict__ bias,
                                             float* __restrict__ hf,
                                             unsigned short* __restrict__ hb) {
    const int node = (blockIdx.x * 256 + threadIdx.x) >> 6;
    const int lane = threadIdx.x & 63;
    if (node >= N_NODES) return;
    const int base = node * N_REL + g0;
    const int gbeg = off[base];
    if (!FIRST && !RELUOUT) {
        if (gbeg == off[base + G]) return;      // nothing to add, hf already valid
    }
    constexpr size_t XSTR = (size_t)N_NODES * DOUT;

    if (DOUT == 128) {
        float ax, ay;
        if (FIRST) { ax = bias[lane * 2]; ay = bias[lane * 2 + 1]; }
        else       { ax = 0.f;            ay = 0.f; }
        int j = gbeg;
        for (int r = 0; r < G; ++r) {
            const int e1 = off[base + r + 1];
            const __half* xr = xw + (size_t)r * XSTR;
            for (; j < e1; ++j) {
                unsigned p = ep[j];
                int   s = p & 0x1FFFF;
                float w = h2f_bits((unsigned short)(p >> 17));
                __half2 hv = *reinterpret_cast<const __half2*>(&xr[(size_t)s * 128 + lane * 2]);
                float2  f  = __half22float2(hv);
                ax += w * f.x;
                ay += w * f.y;
            }
        }
        if (!FIRST) {
            float2 h0 = *reinterpret_cast<const float2*>(&hf[(size_t)node * 128 + lane * 2]);
            ax += h0.x; ay += h0.y;
        }
        if (RELUOUT) {
            unsigned pk = (unsigned)f2bf(fmaxf(ax, 0.f)) |
                          ((unsigned)f2bf(fmaxf(ay, 0.f)) << 16);
            *reinterpret_cast<unsigned*>(&hb[(size_t)node * 128 + lane * 2]) = pk;
        } else {
            *reinterpret_cast<float2*>(&hf[(size_t)node * 128 + lane * 2]) =
                make_float2(ax, ay);
        }
    } else {  // DOUT == 64 (layer 2: never RELUOUT)
        float a = FIRST ? bias[lane] : 0.f;
        int j = gbeg;
        for (int r = 0; r < G; ++r) {
            const int e1 = off[base + r + 1];
            const __half* xr = xw + (size_t)r * XSTR;
            for (; j < e1; ++j) {
                unsigned p = ep[j];
                int   s = p & 0x1FFFF;
                float w = h2f_bits((unsigned short)(p >> 17));
                a += w * __half2float(xr[(size_t)s * 64 + lane]);
            }
        }
        if (!FIRST) a += hf[(size_t)node * 64 + lane];
        hf[(size_t)node * 64 + lane] = a;
    }
}

// ---------------------------------------------------------------------------
// xw3[n,r] = sum_d relu(h2[n,d]) * W3[r,d,0]   (fp32, tiny)
__global__ __launch_bounds__(256) void xw3_kernel(const float* __restrict__ h2,
                                                  const float* __restrict__ W3,
                                                  float* __restrict__ xw3) {
    __shared__ float w[N_REL][D2];
    for (int i = threadIdx.x; i < N_REL * D2; i += 256)
        w[i / D2][i % D2] = W3[i];
    __syncthreads();
    int g = blockIdx.x * 256 + threadIdx.x;
    if (g < N_NODES * N_REL) {
        int n = g >> 3, r = g & 7;
        const float* hp = &h2[(size_t)n * D2];
        float s = 0.f;
#pragma unroll
        for (int d = 0; d < D2; ++d) s += fmaxf(hp[d], 0.f) * w[r][d];
        xw3[g] = s;
    }
}

// Final layer: one thread per dst node; its 8 relation segments are contiguous.
__global__ __launch_bounds__(256) void final_k(const int* __restrict__ off,
                                               const unsigned* __restrict__ ep,
                                               const float* __restrict__ xw3,
                                               const float* __restrict__ b3,
                                               float* __restrict__ out) {
    int d = blockIdx.x * 256 + threadIdx.x;
    if (d >= N_NODES) return;
    float acc = b3[0];
    const int base = d * N_REL;
    int j = off[base];
#pragma unroll
    for (int r = 0; r < N_REL; ++r) {
        const int e1 = off[base + r + 1];
        for (; j < e1; ++j) {
            unsigned p = ep[j];
            int   s = p & 0x1FFFF;
            float w = h2f_bits((unsigned short)(p >> 17));
            acc += w * xw3[(size_t)s * N_REL + r];
        }
    }
    out[d] = acc;
}

// ---------------------------------------------------------------------------
extern "C" void kernel_launch(void* const* d_in, const int* in_sizes, int n_in,
                              void* d_out, int out_size, void* d_ws, size_t ws_size,
                              hipStream_t stream) {
    (void)in_sizes; (void)n_in; (void)out_size;

    const float* z    = (const float*)d_in[0];
    const int*   eidx = (const int*)d_in[1];
    const float* ew   = (const float*)d_in[2];
    const int*   et   = (const int*)d_in[3];
    const float* W1   = (const float*)d_in[4];
    const float* b1   = (const float*)d_in[5];
    const float* W2   = (const float*)d_in[6];
    const float* b2   = (const float*)d_in[7];
    const float* W3   = (const float*)d_in[8];
    const float* b3   = (const float*)d_in[9];

    const int* src = eidx;
    const int* dst = eidx + N_EDGES;

    // ---- choose relation-group size G by available workspace ----
    auto pad = [](size_t b) { return (b + 255) & ~(size_t)255; };
    const size_t sz_off   = pad((size_t)(NBUCKET + 1) * 4);
    const size_t sz_bins  = pad((size_t)NBIN * 4);
    const size_t sz_binsp = pad((size_t)(NBIN + 1) * 4);
    const size_t sz_ep    = pad((size_t)N_EDGES * 4);
    const size_t sz_wt1   = pad((size_t)N_REL * D0 * D1 * 2);
    const size_t sz_wt2   = pad((size_t)N_REL * D1 * D2 * 2);
    const size_t sz_union = pad((size_t)N_NODES * D1 * 2);     // max(temp 13.1MB, h1b 26.2MB)
    const size_t per_rel  = (size_t)N_NODES * D1 * 2;          // 26.2 MB
    const size_t fixed = sz_off + sz_bins + sz_binsp + sz_bins + sz_ep + sz_wt1 + sz_wt2 + sz_union;
    int G;
    if      (ws_size >= fixed + 8 * per_rel)                 G = 8;  // no h1f needed
    else if (ws_size >= fixed + 4 * per_rel + pad((size_t)N_NODES * D1 * 4)) G = 4;
    else                                                     G = 2;  // 141.6 MB, proven safe
    const int NG = N_REL / G;

    // ---- workspace layout ----
    char* ws = (char*)d_ws;
    size_t o = 0;
    auto alloc = [&](size_t bytes) { char* p = ws + o; o += (bytes + 255) & ~(size_t)255; return p; };
    int*      off     = (int*)     alloc((size_t)(NBUCKET + 1) * 4);
    int*      bincnt  = (int*)     alloc((size_t)NBIN * 4);
    int*      binbase = (int*)     alloc((size_t)(NBIN + 1) * 4);
    int*      bincur  = (int*)     alloc((size_t)NBIN * 4);
    unsigned* ep      = (unsigned*)alloc((size_t)N_EDGES * 4);
    unsigned short* Wt1 = (unsigned short*)alloc((size_t)N_REL * D0 * D1 * 2);
    unsigned short* Wt2 = (unsigned short*)alloc((size_t)N_REL * D1 * D2 * 2);
    char*     UNION   =            alloc((size_t)N_NODES * D1 * 2);
    __half*   xw_all  = (__half*)  alloc((size_t)G * per_rel);
    float*    h1f     = (G < 8) ? (float*)alloc((size_t)N_NODES * D1 * 4) : nullptr;

    uint2*          temp = (uint2*)UNION;                       // dead after passB
    unsigned short* h1b  = (unsigned short*)UNION;              // live from last layer-1 agg
    __half*         xw2  = xw_all;                              // layer-2 xw (G x [N,64] fp16)
    float*          h2f  = (float*)((char*)xw_all + (size_t)G * N_NODES * D2 * 2);
    float*          xw3f = (float*)xw_all;                      // layer-3 (xw2 dead by then)
    float* out = (float*)d_out;

    // ---- Build (dst,rel)-sorted CSR via two-level binning ----
    fill0_k<<<(NBIN + 255) / 256, 256, 0, stream>>>(bincnt, NBIN);
    countA_k<<<NBLKA, 256, 0, stream>>>(dst, bincnt);
    scanB_k<<<1, 512, 0, stream>>>(bincnt, binbase, bincur);
    scatterA_k<<<NBLKA, 256, 0, stream>>>(src, dst, ew, et, bincur, temp);
    passB_k<<<NBIN, 512, 0, stream>>>(temp, binbase, off, ep);

    // ---- Weight conversions (bf16, transposed) ----
    cvt_wT_k<<<(N_REL * D0 * D1 + 255) / 256, 256, 0, stream>>>(W1, Wt1, D0, D1, N_REL * D0 * D1);
    cvt_wT_k<<<(N_REL * D1 * D2 + 255) / 256, 256, 0, stream>>>(W2, Wt2, D1, D2, N_REL * D1 * D2);

    constexpr int AGG_BLKS = N_NODES / 4;       // 4 waves (nodes) per 256-thread block

    // ---- Layer 1: 256 -> 128 (A fp32 converted in-kernel) ----
    for (int g = 0; g < NG; ++g) {
        const int g0 = g * G;
        mfma_gemm_b<D0, D1, true><<<dim3(N_NODES / 128, G), 256, 0, stream>>>(
            z, Wt1 + (size_t)g0 * D0 * D1, xw_all);
        const bool first = (g == 0), last = (g == NG - 1);
        if (first && last)        // G == 8
            agg_g<D1, true,  true ><<<AGG_BLKS, 256, 0, stream>>>(off, ep, g0, G, xw_all, b1, h1f, h1b);
        else if (first)
            agg_g<D1, true,  false><<<AGG_BLKS, 256, 0, stream>>>(off, ep, g0, G, xw_all, b1, h1f, h1b);
        else if (!last)
            agg_g<D1, false, false><<<AGG_BLKS, 256, 0, stream>>>(off, ep, g0, G, xw_all, b1, h1f, h1b);
        else
            agg_g<D1, false, true ><<<AGG_BLKS, 256, 0, stream>>>(off, ep, g0, G, xw_all, b1, h1f, h1b);
    }
    // ---- Layer 2: 128 -> 64 (A = h1b bf16) ----
    for (int g = 0; g < NG; ++g) {
        const int g0 = g * G;
        mfma_gemm_b<D1, D2, false><<<dim3(N_NODES / 128, G), 256, 0, stream>>>(
            h1b, Wt2 + (size_t)g0 * D1 * D2, xw2);
        if (g == 0)
            agg_g<D2, true,  false><<<AGG_BLKS, 256, 0, stream>>>(off, ep, g0, G, xw2, b2, h2f, nullptr);
        else
            agg_g<D2, false, false><<<AGG_BLKS, 256, 0, stream>>>(off, ep, g0, G, xw2, b2, h2f, nullptr);
    }
    // ---- Layer 3: 64 -> 1 ----
    xw3_kernel<<<(N_NODES * N_REL + 255) / 256, 256, 0, stream>>>(h2f, W3, xw3f);
    final_k<<<(N_NODES + 255) / 256, 256, 0, stream>>>(off, ep, xw3f, b3, out);
}

// Round 8
// 655.607 us; speedup vs baseline: 5.5096x; 1.3662x over previous
//
#include <hip/hip_runtime.h>
#include <hip/hip_bf16.h>
#include <hip/hip_fp16.h>
#include <cstdint>

// Problem constants (fixed by setup_inputs)
#define N_NODES 102400
#define N_EDGES 1638400
#define N_REL   8
#define D0      256
#define D1      128
#define D2      64

#define WIN     256                 // dsts per coarse bin
#define NBIN    (N_NODES / WIN)     // 400
#define CHA     8192                // edges per partition block
#define NBLKA   (N_EDGES / CHA)     // 200 (exact)

typedef __attribute__((ext_vector_type(8))) short          s16x8;
typedef __attribute__((ext_vector_type(8))) unsigned short u16x8;
typedef __attribute__((ext_vector_type(4))) float          f32x4;

__device__ __forceinline__ unsigned short f2bf(float f) {
    unsigned u = __float_as_uint(f);
    u += 0x7fffu + ((u >> 16) & 1u);           // RNE
    return (unsigned short)(u >> 16);
}
__device__ __forceinline__ float h2f_bits(unsigned short u) {
    __half_raw r; r.x = u;
    return __half2float(__half(r));
}

// ---------------------------------------------------------------------------
__global__ __launch_bounds__(256) void fill0_k(int* __restrict__ p, int total) {
    int i = blockIdx.x * 256 + threadIdx.x;
    if (i < total) p[i] = 0;
}

// Coarse bin counts (bin = dst >> 8), LDS-aggregated
__global__ __launch_bounds__(256) void countA_k(const int* __restrict__ dst,
                                                int* __restrict__ bincnt) {
    __shared__ int h[NBIN];
    const int t  = threadIdx.x;
    const int e0 = blockIdx.x * CHA;
    for (int i = t; i < NBIN; i += 256) h[i] = 0;
    __syncthreads();
#pragma unroll
    for (int i = 0; i < CHA / 256; ++i) {
        int e = e0 + t + i * 256;
        if (e < N_EDGES) atomicAdd(&h[dst[e] >> 8], 1);
    }
    __syncthreads();
    for (int i = t; i < NBIN; i += 256) {
        int c = h[i];
        if (c) atomicAdd(&bincnt[i], c);
    }
}

__device__ __forceinline__ int block_scan_excl_512(int v, int* sA, int* sB, int t) {
    sA[t] = v;
    __syncthreads();
    int* s = sA; int* d = sB;
    for (int o = 1; o < 512; o <<= 1) {
        int x = s[t];
        if (t >= o) x += s[t - o];
        d[t] = x;
        __syncthreads();
        int* tmp = s; s = d; d = tmp;
    }
    return s[t] - v;
}

// Exclusive scan of 400 bin counts (single block)
__global__ __launch_bounds__(512) void scanB_k(const int* __restrict__ bincnt,
                                               int* __restrict__ binbase,
                                               int* __restrict__ bincur) {
    __shared__ int sA[512], sB[512];
    const int t = threadIdx.x;
    int v = (t < NBIN) ? bincnt[t] : 0;
    int excl = block_scan_excl_512(v, sA, sB, t);
    if (t < NBIN) { binbase[t] = excl; bincur[t] = excl; }
    if (t == 0) binbase[NBIN] = N_EDGES;
}

// Partition edges into coarse bins:
//   temp[pos] = { g = et*N + src ,  (half_bits(ew) << 8) | (dst & 255) }
// (ew in [0,1) -> half bits fit 14 bits)
__global__ __launch_bounds__(256) void scatterA_k(const int* __restrict__ src,
                                                  const int* __restrict__ dst,
                                                  const float* __restrict__ ew,
                                                  const int* __restrict__ et,
                                                  int* __restrict__ bincur,
                                                  uint2* __restrict__ temp) {
    __shared__ int h[NBIN];
    const int t  = threadIdx.x;
    const int e0 = blockIdx.x * CHA;
    for (int i = t; i < NBIN; i += 256) h[i] = 0;
    __syncthreads();
#pragma unroll
    for (int i = 0; i < CHA / 256; ++i) {
        int e = e0 + t + i * 256;
        if (e < N_EDGES) atomicAdd(&h[dst[e] >> 8], 1);
    }
    __syncthreads();
    for (int i = t; i < NBIN; i += 256) {
        int c = h[i];
        h[i] = c ? atomicAdd(&bincur[i], c) : 0;
    }
    __syncthreads();
#pragma unroll
    for (int i = 0; i < CHA / 256; ++i) {
        int e = e0 + t + i * 256;
        if (e < N_EDGES) {
            int d   = dst[e];
            int bin = d >> 8;
            unsigned hb = (unsigned)(__half_raw(__float2half(ew[e])).x);
            unsigned g  = (unsigned)(et[e] * N_NODES + src[e]);
            int pos = atomicAdd(&h[bin], 1);
            temp[pos] = make_uint2(g, (hb << 8) | (unsigned)(d & 255));
        }
    }
}

// Per-bin finalize: node-level CSR offsets + dst-sorted edge arrays {eg, ewh}
__global__ __launch_bounds__(512) void passB_k(const uint2* __restrict__ temp,
                                               const int* __restrict__ binbase,
                                               int* __restrict__ off,
                                               unsigned* __restrict__ eg,
                                               unsigned short* __restrict__ ewh) {
    __shared__ int hist[WIN];
    __shared__ int sA[512], sB[512];
    const int b    = blockIdx.x;
    const int t    = threadIdx.x;
    const int beg  = binbase[b], end = binbase[b + 1];
    const int key0 = b * WIN;
    if (t < WIN) hist[t] = 0;
    __syncthreads();
    for (int j = beg + t; j < end; j += 512)
        atomicAdd(&hist[temp[j].y & 255], 1);
    __syncthreads();
    int v = (t < WIN) ? hist[t] : 0;
    int excl = block_scan_excl_512(v, sA, sB, t) + beg;
    if (t < WIN) {
        off[key0 + t] = excl;
        hist[t] = excl;                         // cursor
    }
    __syncthreads();
    for (int j = beg + t; j < end; j += 512) {
        uint2 e = temp[j];
        int pos = atomicAdd(&hist[e.y & 255], 1);
        eg[pos]  = e.x;
        ewh[pos] = (unsigned short)(e.y >> 8);
    }
    if (b == 0 && t == 0) off[N_NODES] = N_EDGES;
}

// ---------------------------------------------------------------------------
// W[R][K][Nn] fp32 -> Wt[R][Nn][K] bf16 (transpose; tiny, launched once)
__global__ __launch_bounds__(256) void cvt_wT_k(const float* __restrict__ in,
                                                unsigned short* __restrict__ out,
                                                int K, int Nn, int total) {
    int o = blockIdx.x * 256 + threadIdx.x;
    if (o < total) {
        int kn = K * Nn;
        int r = o / kn, rem = o % kn;
        int n = rem / K, k = rem % K;
        out[o] = f2bf(in[r * kn + k * Nn + n]);
    }
}

// ---------------------------------------------------------------------------
// bf16 MFMA GEMM, batched over blockIdx.y = relation.
// A is fp32 (converted during LDS staging) when AF32, else bf16. C fp16.
template<int DIN, int DOUT, bool AF32>
__global__ __launch_bounds__(256) void mfma_gemm_b(const void* __restrict__ Av,
                                                   const unsigned short* __restrict__ Bt0,
                                                   __half* __restrict__ C0) {
    constexpr int BM  = 128;
    constexpr int BK  = 64;
    constexpr int BN  = DOUT;
    constexpr int LDK = BK + 8;
    constexpr int FM  = (BM / 2) / 16;          // 4
    constexpr int FN  = (BN / 2) / 16;          // 4 (BN=128) or 2 (BN=64)

    __shared__ __align__(16) unsigned short As[BM][LDK];
    __shared__ __align__(16) unsigned short Bs[BN][LDK];

    const unsigned short* Bt = Bt0 + (size_t)blockIdx.y * DIN * DOUT;
    __half*               C  = C0  + (size_t)blockIdx.y * N_NODES * DOUT;

    const int tid  = threadIdx.x;
    const int wave = tid >> 6;
    const int lane = tid & 63;
    const int lr   = lane & 15;
    const int kq   = lane >> 4;
    const int wm   = (wave >> 1) * (BM / 2);
    const int wn   = (wave & 1) * (BN / 2);
    const int row0 = blockIdx.x * BM;

    f32x4 acc[FM][FN];
#pragma unroll
    for (int i = 0; i < FM; ++i)
#pragma unroll
        for (int j = 0; j < FN; ++j) acc[i][j] = (f32x4){0.f, 0.f, 0.f, 0.f};

    for (int kt = 0; kt < DIN; kt += BK) {
        constexpr int NA = BM * BK / 8;
#pragma unroll
        for (int i = 0; i < NA / 256; ++i) {
            int idx = tid + i * 256;
            int r = idx >> 3;
            int c = (idx & 7) * 8;
            u16x8 v;
            if constexpr (AF32) {
                const float* ap = (const float*)Av + (size_t)(row0 + r) * DIN + kt + c;
                float4 u0 = *reinterpret_cast<const float4*>(ap);
                float4 u1 = *reinterpret_cast<const float4*>(ap + 4);
                v[0] = (short)f2bf(u0.x); v[1] = (short)f2bf(u0.y);
                v[2] = (short)f2bf(u0.z); v[3] = (short)f2bf(u0.w);
                v[4] = (short)f2bf(u1.x); v[5] = (short)f2bf(u1.y);
                v[6] = (short)f2bf(u1.z); v[7] = (short)f2bf(u1.w);
            } else {
                v = *reinterpret_cast<const u16x8*>(
                    (const unsigned short*)Av + (size_t)(row0 + r) * DIN + kt + c);
            }
            *reinterpret_cast<u16x8*>(&As[r][c]) = v;
        }
        constexpr int NB = BN * BK / 8;
#pragma unroll
        for (int i = 0; i < NB / 256; ++i) {
            int idx = tid + i * 256;
            int r = idx >> 3;
            int c = (idx & 7) * 8;
            u16x8 v = *reinterpret_cast<const u16x8*>(&Bt[(size_t)r * DIN + kt + c]);
            *reinterpret_cast<u16x8*>(&Bs[r][c]) = v;
        }
        __syncthreads();

#pragma unroll
        for (int ks = 0; ks < BK; ks += 32) {
            s16x8 af[FM], bfr[FN];
#pragma unroll
            for (int mi = 0; mi < FM; ++mi)
                af[mi] = *reinterpret_cast<const s16x8*>(&As[wm + mi * 16 + lr][ks + kq * 8]);
#pragma unroll
            for (int ni = 0; ni < FN; ++ni)
                bfr[ni] = *reinterpret_cast<const s16x8*>(&Bs[wn + ni * 16 + lr][ks + kq * 8]);
#pragma unroll
            for (int mi = 0; mi < FM; ++mi)
#pragma unroll
                for (int ni = 0; ni < FN; ++ni)
                    acc[mi][ni] = __builtin_amdgcn_mfma_f32_16x16x32_bf16(
                        af[mi], bfr[ni], acc[mi][ni], 0, 0, 0);
        }
        __syncthreads();
    }

#pragma unroll
    for (int mi = 0; mi < FM; ++mi) {
#pragma unroll
        for (int ni = 0; ni < FN; ++ni) {
#pragma unroll
            for (int reg = 0; reg < 4; ++reg) {
                int rrow = row0 + wm + mi * 16 + kq * 4 + reg;
                int ccol = wn + ni * 16 + lr;
                C[(size_t)rrow * DOUT + ccol] = __float2half(acc[mi][ni][reg]);
            }
        }
    }
}

// ---------------------------------------------------------------------------
// Flat CSR gather-reduce over ALL relations at once: one wave per dst node.
// Gather address = xw + g*DOUT (xw laid out [rel][node][DOUT] fp16).
// 4-way unrolled: 4 independent gathers in flight per wave.
// RELUOUT: hb = bf16(relu(bias + acc)); else hf = bias + acc (fp32).
template<int DOUT, bool RELUOUT>
__global__ __launch_bounds__(256) void agg_flat(const int* __restrict__ off,
                                                const unsigned* __restrict__ eg,
                                                const unsigned short* __restrict__ ewh,
                                                const __half* __restrict__ xw,
                                                const float* __restrict__ bias,
                                                float* __restrict__ hf,
                                                unsigned short* __restrict__ hb) {
    const int node = (blockIdx.x * 256 + threadIdx.x) >> 6;
    const int lane = threadIdx.x & 63;
    if (node >= N_NODES) return;
    const int beg = off[node], end = off[node + 1];

    if (DOUT == 128) {
        float ax = bias[lane * 2], ay = bias[lane * 2 + 1];
        int j = beg;
        for (; j + 4 <= end; j += 4) {
            unsigned g0 = eg[j], g1 = eg[j + 1], g2 = eg[j + 2], g3 = eg[j + 3];
            float w0 = h2f_bits(ewh[j]),     w1 = h2f_bits(ewh[j + 1]);
            float w2 = h2f_bits(ewh[j + 2]), w3 = h2f_bits(ewh[j + 3]);
            __half2 v0 = *reinterpret_cast<const __half2*>(&xw[(size_t)g0 * 128 + lane * 2]);
            __half2 v1 = *reinterpret_cast<const __half2*>(&xw[(size_t)g1 * 128 + lane * 2]);
            __half2 v2 = *reinterpret_cast<const __half2*>(&xw[(size_t)g2 * 128 + lane * 2]);
            __half2 v3 = *reinterpret_cast<const __half2*>(&xw[(size_t)g3 * 128 + lane * 2]);
            float2 f0 = __half22float2(v0), f1 = __half22float2(v1);
            float2 f2 = __half22float2(v2), f3 = __half22float2(v3);
            ax += w0 * f0.x + w1 * f1.x + w2 * f2.x + w3 * f3.x;
            ay += w0 * f0.y + w1 * f1.y + w2 * f2.y + w3 * f3.y;
        }
        for (; j < end; ++j) {
            unsigned g = eg[j];
            float    w = h2f_bits(ewh[j]);
            __half2  v = *reinterpret_cast<const __half2*>(&xw[(size_t)g * 128 + lane * 2]);
            float2   f = __half22float2(v);
            ax += w * f.x;
            ay += w * f.y;
        }
        if (RELUOUT) {
            unsigned pk = (unsigned)f2bf(fmaxf(ax, 0.f)) |
                          ((unsigned)f2bf(fmaxf(ay, 0.f)) << 16);
            *reinterpret_cast<unsigned*>(&hb[(size_t)node * 128 + lane * 2]) = pk;
        } else {
            *reinterpret_cast<float2*>(&hf[(size_t)node * 128 + lane * 2]) =
                make_float2(ax, ay);
        }
    } else {  // DOUT == 64
        float a = bias[lane];
        int j = beg;
        for (; j + 4 <= end; j += 4) {
            unsigned g0 = eg[j], g1 = eg[j + 1], g2 = eg[j + 2], g3 = eg[j + 3];
            float w0 = h2f_bits(ewh[j]),     w1 = h2f_bits(ewh[j + 1]);
            float w2 = h2f_bits(ewh[j + 2]), w3 = h2f_bits(ewh[j + 3]);
            float f0 = __half2float(xw[(size_t)g0 * 64 + lane]);
            float f1 = __half2float(xw[(size_t)g1 * 64 + lane]);
            float f2 = __half2float(xw[(size_t)g2 * 64 + lane]);
            float f3 = __half2float(xw[(size_t)g3 * 64 + lane]);
            a += w0 * f0 + w1 * f1 + w2 * f2 + w3 * f3;
        }
        for (; j < end; ++j)
            a += h2f_bits(ewh[j]) * __half2float(xw[(size_t)eg[j] * 64 + lane]);
        hf[(size_t)node * 64 + lane] = a;
    }
}

// ---------------------------------------------------------------------------
// xw3[r*N + n] = sum_d relu(h2[n,d]) * W3[r,d,0]   ([rel][node] layout!)
__global__ __launch_bounds__(256) void xw3_kernel(const float* __restrict__ h2,
                                                  const float* __restrict__ W3,
                                                  float* __restrict__ xw3) {
    __shared__ float w[D2];
    const int r = blockIdx.y;
    for (int i = threadIdx.x; i < D2; i += 256) w[i] = W3[r * D2 + i];
    __syncthreads();
    int n = blockIdx.x * 256 + threadIdx.x;
    if (n < N_NODES) {
        const float4* hp = reinterpret_cast<const float4*>(h2 + (size_t)n * D2);
        float s = 0.f;
#pragma unroll
        for (int d4 = 0; d4 < D2 / 4; ++d4) {
            float4 v = hp[d4];
            s += fmaxf(v.x, 0.f) * w[d4 * 4]     + fmaxf(v.y, 0.f) * w[d4 * 4 + 1] +
                 fmaxf(v.z, 0.f) * w[d4 * 4 + 2] + fmaxf(v.w, 0.f) * w[d4 * 4 + 3];
        }
        xw3[(size_t)r * N_NODES + n] = s;
    }
}

// Final layer: one thread per dst node, flat edge range, 4-way unroll.
__global__ __launch_bounds__(256) void final_k(const int* __restrict__ off,
                                               const unsigned* __restrict__ eg,
                                               const unsigned short* __restrict__ ewh,
                                               const float* __restrict__ xw3,
                                               const float* __restrict__ b3,
                                               float* __restrict__ out) {
    int d = blockIdx.x * 256 + threadIdx.x;
    if (d >= N_NODES) return;
    float acc = b3[0];
    const int beg = off[d], end = off[d + 1];
    int j = beg;
    for (; j + 4 <= end; j += 4) {
        float w0 = h2f_bits(ewh[j]),     w1 = h2f_bits(ewh[j + 1]);
        float w2 = h2f_bits(ewh[j + 2]), w3 = h2f_bits(ewh[j + 3]);
        float x0 = xw3[eg[j]],     x1 = xw3[eg[j + 1]];
        float x2 = xw3[eg[j + 2]], x3 = xw3[eg[j + 3]];
        acc += w0 * x0 + w1 * x1 + w2 * x2 + w3 * x3;
    }
    for (; j < end; ++j)
        acc += h2f_bits(ewh[j]) * xw3[eg[j]];
    out[d] = acc;
}

// ---------------------------------------------------------------------------
extern "C" void kernel_launch(void* const* d_in, const int* in_sizes, int n_in,
                              void* d_out, int out_size, void* d_ws, size_t ws_size,
                              hipStream_t stream) {
    (void)in_sizes; (void)n_in; (void)out_size; (void)ws_size;

    const float* z    = (const float*)d_in[0];
    const int*   eidx = (const int*)d_in[1];
    const float* ew   = (const float*)d_in[2];
    const int*   et   = (const int*)d_in[3];
    const float* W1   = (const float*)d_in[4];
    const float* b1   = (const float*)d_in[5];
    const float* W2   = (const float*)d_in[6];
    const float* b2   = (const float*)d_in[7];
    const float* W3   = (const float*)d_in[8];
    const float* b3   = (const float*)d_in[9];

    const int* src = eidx;
    const int* dst = eidx + N_EDGES;

    // ---- workspace layout (~247 MB; round-5 counters prove ws >= 257 MB) ----
    char* ws = (char*)d_ws;
    size_t o = 0;
    auto alloc = [&](size_t bytes) { char* p = ws + o; o += (bytes + 255) & ~(size_t)255; return p; };
    int*      off     = (int*)     alloc((size_t)(N_NODES + 1) * 4);   // 0.41 MB
    int*      bincnt  = (int*)     alloc((size_t)NBIN * 4);
    int*      binbase = (int*)     alloc((size_t)(NBIN + 1) * 4);
    int*      bincur  = (int*)     alloc((size_t)NBIN * 4);
    unsigned* eg      = (unsigned*)alloc((size_t)N_EDGES * 4);         // 6.55 MB
    unsigned short* ewh = (unsigned short*)alloc((size_t)N_EDGES * 2); // 3.28 MB
    unsigned short* Wt1 = (unsigned short*)alloc((size_t)N_REL * D0 * D1 * 2); // 0.52 MB
    unsigned short* Wt2 = (unsigned short*)alloc((size_t)N_REL * D1 * D2 * 2); // 0.13 MB
    char*     UNION   =            alloc((size_t)N_NODES * D1 * 2);    // 26.2 MB
    __half*   xw_all  = (__half*)  alloc((size_t)N_REL * N_NODES * D1 * 2); // 210 MB

    uint2*          temp = (uint2*)UNION;                   // 13.1 MB, dead after passB
    unsigned short* h1b  = (unsigned short*)UNION;          // bf16 h1, live from L1 agg
    __half*         xw2  = xw_all;                          // L2 xw: [8][N][64] fp16 (105 MB)
    float*          h2f  = (float*)((char*)xw_all + (size_t)N_REL * N_NODES * D2 * 2); // +105 MB
    float*          xw3f = (float*)xw_all;                  // [8][N] f32 (3.3 MB), xw2 dead
    float* out = (float*)d_out;

    // ---- Build dst-sorted edge arrays via two-level binning ----
    fill0_k<<<(NBIN + 255) / 256, 256, 0, stream>>>(bincnt, NBIN);
    countA_k<<<NBLKA, 256, 0, stream>>>(dst, bincnt);
    scanB_k<<<1, 512, 0, stream>>>(bincnt, binbase, bincur);
    scatterA_k<<<NBLKA, 256, 0, stream>>>(src, dst, ew, et, bincur, temp);
    passB_k<<<NBIN, 512, 0, stream>>>(temp, binbase, off, eg, ewh);

    // ---- Weight conversions (bf16, transposed) ----
    cvt_wT_k<<<(N_REL * D0 * D1 + 255) / 256, 256, 0, stream>>>(W1, Wt1, D0, D1, N_REL * D0 * D1);
    cvt_wT_k<<<(N_REL * D1 * D2 + 255) / 256, 256, 0, stream>>>(W2, Wt2, D1, D2, N_REL * D1 * D2);

    constexpr int AGG_BLKS = N_NODES / 4;       // 4 waves (nodes) per 256-thread block

    // ---- Layer 1: 256 -> 128 (A fp32 converted in-kernel; all 8 relations) ----
    mfma_gemm_b<D0, D1, true><<<dim3(N_NODES / 128, N_REL), 256, 0, stream>>>(
        z, Wt1, xw_all);
    agg_flat<D1, true><<<AGG_BLKS, 256, 0, stream>>>(off, eg, ewh, xw_all, b1, nullptr, h1b);

    // ---- Layer 2: 128 -> 64 (A = h1b bf16) ----
    mfma_gemm_b<D1, D2, false><<<dim3(N_NODES / 128, N_REL), 256, 0, stream>>>(
        h1b, Wt2, xw2);
    agg_flat<D2, false><<<AGG_BLKS, 256, 0, stream>>>(off, eg, ewh, xw2, b2, h2f, nullptr);

    // ---- Layer 3: 64 -> 1 ----
    xw3_kernel<<<dim3((N_NODES + 255) / 256, N_REL), 256, 0, stream>>>(h2f, W3, xw3f);
    final_k<<<(N_NODES + 255) / 256, 256, 0, stream>>>(off, eg, ewh, xw3f, b3, out);
}